// Round 9
// baseline (1592.437 us; speedup 1.0000x reference)
//
#include <hip/hip_runtime.h>
#include <math.h>

typedef __attribute__((ext_vector_type(8))) short bf16x8;
typedef __attribute__((ext_vector_type(4))) float f32x4;

#define DEVI __device__ __forceinline__

DEVI short f2bf(float f) {
  unsigned u = __builtin_bit_cast(unsigned, f);
  return (short)((u + 0x7fffu + ((u >> 16) & 1u)) >> 16);
}
DEVI float bf2f(short s) {
  unsigned u = ((unsigned)(unsigned short)s) << 16;
  return __builtin_bit_cast(float, u);
}

DEVI float silu_f(float v) { return v / (1.0f + expf(-v)); }

DEVI void async16(const void* g, void* l) {
  __builtin_amdgcn_global_load_lds(
      (const __attribute__((address_space(1))) void*)g,
      (__attribute__((address_space(3))) void*)l, 16, 0, 0);
}

template <int N>
DEVI void waitvm() { asm volatile("s_waitcnt vmcnt(%0)" ::"i"(N) : "memory"); }
DEVI void barrier_mem() { asm volatile("s_barrier" ::: "memory"); }
DEVI void lgkm0_sb() {
  asm volatile("s_waitcnt lgkmcnt(0)" ::: "memory");
  __builtin_amdgcn_sched_barrier(0);
}

// bijective XCD swizzle (nwg % 8 == 0 always here), M-tile fastest within XCD chunk
template <int NROWT>
DEVI void tile_map(int* bx, int* by) {
  const int nwg = gridDim.x;
  const int lin = blockIdx.x;
  const int q = nwg >> 3;
  const int wgid = (lin & 7) * q + (lin >> 3);
  *by = wgid % NROWT;
  *bx = wgid / NROWT;
}

// LDS: rows of 64B (32 bf16 k-slice), 4x16B slots, slot XOR-swizzled by (row>>1)&3.
// global_load_lds writes linearly -> pre-swizzle the per-lane GLOBAL source slot
// (rule #21). Verified R3-R8: SQ_LDS_BANK_CONFLICT == 0.
#define SWZ(r) ((ks ^ (((r) >> 1) & 3)) << 4)

// =============== vocab GEMM v3: 256x128, BK=32, 3-ring 72KB, 2 blocks/CU ======
// 512 thr, 8 waves (4M x 2N), wave 64x64. Depth-2 counted vmcnt(3); single
// phase per K-tile; co-resident block hides drain + epilogue (m97 mechanism).
__global__ __launch_bounds__(512, 4) void voc_k(const short* __restrict__ A,
                                                const short* __restrict__ BT,
                                                const float* __restrict__ bias,
                                                float* __restrict__ outp,
                                                int N, int K) {
  __shared__ __align__(16) char lds[3 * 24576];
  int bx, by;
  tile_map<16>(&bx, &by);
  const int row0 = by << 8, col0 = bx << 7;
  const int t = threadIdx.x, w = t >> 6, lane = t & 63;
  const int wm = w >> 1, wn = w & 1;
  const int lr = lane & 15, ks = lane >> 4;
  f32x4 acc[4][4] = {};

  const int sslot = (t & 3) ^ ((t >> 3) & 3);
  const char* gA = (const char*)A + ((size_t)(row0 + (t >> 2)) * K) * 2 + sslot * 16;
  const char* gB = (const char*)BT + ((size_t)(col0 + (t >> 2)) * K) * 2 + sslot * 16;
  const size_t cstep = (size_t)K << 8;  // 128 rows fwd (512 thr cover 128 rows)
  const int t16 = t << 4;
  const int nkt = K >> 5;

  // buffer 24KB: A 16K @0 (rows 0-127 @0, 128-255 @8192), B 8K @16384
#define SV(nb, kt)                                                            \
  {                                                                           \
    const size_t co = (size_t)(kt) << 6;                                      \
    async16(gA + co, (nb) + t16);                                             \
    async16(gA + cstep + co, (nb) + 8192 + t16);                              \
    async16(gB + co, (nb) + 16384 + t16);                                     \
  }

  SV(lds, 0);
  SV(lds + 24576, 1);

  for (int kt = 0; kt < nkt; ++kt) {
    const char* base = lds + (kt % 3) * 24576;
    char* nb = lds + ((kt + 2) % 3) * 24576;
    if (kt + 1 < nkt) waitvm<3>();  // tile kt done; kt+1 (3 loads) in flight
    else waitvm<0>();
    barrier_mem();
    if (kt + 2 < nkt) SV(nb, kt + 2);
    bf16x8 af[4], bfr[4];
#pragma unroll
    for (int m = 0; m < 4; ++m) {
      const int r = (wm << 6) + (m << 4) + lr;
      af[m] = *(const bf16x8*)(base + r * 64 + SWZ(r));
    }
#pragma unroll
    for (int n = 0; n < 4; ++n) {
      const int rb = (wn << 6) + (n << 4) + lr;
      bfr[n] = *(const bf16x8*)(base + 16384 + rb * 64 + SWZ(rb));
    }
    lgkm0_sb();
    __builtin_amdgcn_s_setprio(1);
#pragma unroll
    for (int m = 0; m < 4; ++m)
#pragma unroll
      for (int n = 0; n < 4; ++n)
        acc[m][n] = __builtin_amdgcn_mfma_f32_16x16x32_bf16(af[m], bfr[n], acc[m][n], 0, 0, 0);
    __builtin_amdgcn_s_setprio(0);
    __builtin_amdgcn_sched_barrier(0);
  }

  const int orow = row0 + (wm << 6) + (ks << 2);
  const int ocol = col0 + (wn << 6) + lr;
#pragma unroll
  for (int m = 0; m < 4; ++m) {
#pragma unroll
    for (int n = 0; n < 4; ++n) {
      const int c = ocol + (n << 4);
      const float bv = bias[c];
#pragma unroll
      for (int i = 0; i < 4; ++i) {
        const int r = orow + (m << 4) + i;
        outp[(size_t)r * N + c] = acc[m][n][i] + bv;
      }
    }
  }
#undef SV
}

// =============== dual GEMM v3: 128x128, BK=32, 3-ring 72KB, 2 blocks/CU =======
// bf16 out = (A@B1+b1)*silu(A@B2+b2). 256 thr, 4 waves (2M x 2N), wave 64x64 dual.
__global__ __launch_bounds__(256, 2) void dual_k(const short* __restrict__ A,
                                                 const short* __restrict__ BT1,
                                                 const short* __restrict__ BT2,
                                                 const float* __restrict__ bias1,
                                                 const float* __restrict__ bias2,
                                                 short* __restrict__ outp,
                                                 int N, int K) {
  __shared__ __align__(16) char lds[3 * 24576];
  int bx, by;
  tile_map<32>(&bx, &by);
  const int row0 = by << 7, col0 = bx << 7;
  const int t = threadIdx.x, w = t >> 6, lane = t & 63;
  const int wm = w >> 1, wn = w & 1;
  const int lr = lane & 15, ks = lane >> 4;
  f32x4 acc1[4][4] = {}, acc2[4][4] = {};

  const int sslot = (t & 3) ^ ((t >> 3) & 3);
  const char* gA = (const char*)A + ((size_t)(row0 + (t >> 2)) * K) * 2 + sslot * 16;
  const char* gB1 = (const char*)BT1 + ((size_t)(col0 + (t >> 2)) * K) * 2 + sslot * 16;
  const char* gB2 = (const char*)BT2 + ((size_t)(col0 + (t >> 2)) * K) * 2 + sslot * 16;
  const size_t cstep = (size_t)K << 7;  // 64 rows fwd (256 thr cover 64 rows)
  const int t16 = t << 4;
  const int nkt = K >> 5;

  // buffer 24KB: A 8K @0, B1 8K @8192, B2 8K @16384
#define SD(nb, kt)                                                            \
  {                                                                           \
    const size_t co = (size_t)(kt) << 6;                                      \
    async16(gA + co, (nb) + t16);                                             \
    async16(gA + cstep + co, (nb) + 4096 + t16);                              \
    async16(gB1 + co, (nb) + 8192 + t16);                                     \
    async16(gB1 + cstep + co, (nb) + 12288 + t16);                            \
    async16(gB2 + co, (nb) + 16384 + t16);                                    \
    async16(gB2 + cstep + co, (nb) + 20480 + t16);                            \
  }

  SD(lds, 0);
  SD(lds + 24576, 1);

  for (int kt = 0; kt < nkt; ++kt) {
    const char* base = lds + (kt % 3) * 24576;
    char* nb = lds + ((kt + 2) % 3) * 24576;
    if (kt + 1 < nkt) waitvm<6>();
    else waitvm<0>();
    barrier_mem();
    if (kt + 2 < nkt) SD(nb, kt + 2);
    bf16x8 af[4], b1r[4], b2r[4];
#pragma unroll
    for (int m = 0; m < 4; ++m) {
      const int r = (wm << 6) + (m << 4) + lr;
      af[m] = *(const bf16x8*)(base + r * 64 + SWZ(r));
    }
#pragma unroll
    for (int n = 0; n < 4; ++n) {
      const int rb = (wn << 6) + (n << 4) + lr;
      b1r[n] = *(const bf16x8*)(base + 8192 + rb * 64 + SWZ(rb));
      b2r[n] = *(const bf16x8*)(base + 16384 + rb * 64 + SWZ(rb));
    }
    lgkm0_sb();
    __builtin_amdgcn_s_setprio(1);
#pragma unroll
    for (int m = 0; m < 4; ++m)
#pragma unroll
      for (int n = 0; n < 4; ++n) {
        acc1[m][n] = __builtin_amdgcn_mfma_f32_16x16x32_bf16(af[m], b1r[n], acc1[m][n], 0, 0, 0);
        acc2[m][n] = __builtin_amdgcn_mfma_f32_16x16x32_bf16(af[m], b2r[n], acc2[m][n], 0, 0, 0);
      }
    __builtin_amdgcn_s_setprio(0);
    __builtin_amdgcn_sched_barrier(0);
  }

  const int orow = row0 + (wm << 6) + (ks << 2);
  const int ocol = col0 + (wn << 6) + lr;
#pragma unroll
  for (int m = 0; m < 4; ++m) {
#pragma unroll
    for (int n = 0; n < 4; ++n) {
      const int c = ocol + (n << 4);
      const float bv1 = bias1[c], bv2 = bias2[c];
#pragma unroll
      for (int i = 0; i < 4; ++i) {
        const int r = orow + (m << 4) + i;
        outp[(size_t)r * N + c] = f2bf((acc1[m][n][i] + bv1) * silu_f(acc2[m][n][i] + bv2));
      }
    }
  }
#undef SD
}

// =============== TRIPLE shared-A GEMM (z, za, ya), counted waits ==============
// zb = (A@B1+b1)*silu(A@B2+b2); yab = A@B3+b3.  BM=64, BN=128, 4 waves, NBUF=2.
__global__ __launch_bounds__(256, 2) void triple_k(const short* __restrict__ A,
                                                   const short* __restrict__ BT1,
                                                   const short* __restrict__ BT2,
                                                   const short* __restrict__ BT3,
                                                   const float* __restrict__ b1,
                                                   const float* __restrict__ b2,
                                                   const float* __restrict__ b3,
                                                   short* __restrict__ zout,
                                                   short* __restrict__ yaout,
                                                   int N, int K) {
  constexpr int PBB = 28672;  // A 4K + 3 x B 8K
  __shared__ __align__(16) char lds[2 * PBB];
  int bx, by;
  tile_map<64>(&bx, &by);
  const int row0 = by << 6, col0 = bx << 7;
  const int t = threadIdx.x, w = t >> 6, lane = t & 63;
  const int wr = w >> 1, wc = w & 1;
  const int lr = lane & 15, ks = lane >> 4;
  f32x4 acc1[2][4] = {}, acc2[2][4] = {}, acc3[2][4] = {};

  const int sslot = (t & 3) ^ ((t >> 3) & 3);
  const char* gA = (const char*)A + ((size_t)(row0 + (t >> 2)) * K) * 2 + sslot * 16;
  const size_t brow = ((size_t)(col0 + (t >> 2)) * K) * 2 + sslot * 16;
  const char* gB1 = (const char*)BT1 + brow;
  const char* gB2 = (const char*)BT2 + brow;
  const char* gB3 = (const char*)BT3 + brow;
  const size_t cstep = (size_t)K * 128;  // 64 rows fwd
  const int t16 = t << 4;
  const int nkt = K >> 5;

#define STA(nb, kt) async16(gA + (size_t)(kt) * 64, (nb) + t16)
#define STB(nb, kt, gp, off)                                                  \
  {                                                                           \
    const size_t co = (size_t)(kt) * 64;                                      \
    async16((gp) + co, (nb) + (off) + t16);                                   \
    async16((gp) + cstep + co, (nb) + (off) + 4096 + t16);                    \
  }

  { char* nb = lds; STA(nb, 0); STB(nb, 0, gB1, 4096); STB(nb, 0, gB2, 12288); STB(nb, 0, gB3, 20480); }

  for (int kt = 0; kt < nkt; ++kt) {
    const int ktn = kt + 1;
    const char* base = lds + (kt & 1) * PBB;
    char* nb = lds + (ktn & 1) * PBB;
    bf16x8 af[2], bfr[4];
    // phase 1: B1 (z-pre) + A reads; need kt's A,B1 done -> allow kt's B2,B3 (4)
    waitvm<4>();
    barrier_mem();
    if (ktn < nkt) { STA(nb, ktn); STB(nb, ktn, gB1, 4096); }
#pragma unroll
    for (int m = 0; m < 2; ++m) {
      const int r = (wr << 5) + (m << 4) + lr;
      af[m] = *(const bf16x8*)(base + r * 64 + SWZ(r));
    }
#pragma unroll
    for (int n = 0; n < 4; ++n) {
      const int rb = (wc << 6) + (n << 4) + lr;
      bfr[n] = *(const bf16x8*)(base + 4096 + rb * 64 + SWZ(rb));
    }
    lgkm0_sb();
    __builtin_amdgcn_s_setprio(1);
#pragma unroll
    for (int m = 0; m < 2; ++m)
#pragma unroll
      for (int n = 0; n < 4; ++n)
        acc1[m][n] = __builtin_amdgcn_mfma_f32_16x16x32_bf16(af[m], bfr[n], acc1[m][n], 0, 0, 0);
    __builtin_amdgcn_s_setprio(0);
    __builtin_amdgcn_sched_barrier(0);
    // phase 2: B2 (za-pre); need kt's B2 -> allow kt B3(2) + kt+1 A,B1(3)
    if (ktn < nkt) waitvm<5>();
    else waitvm<2>();
    barrier_mem();
    if (ktn < nkt) STB(nb, ktn, gB2, 12288);
#pragma unroll
    for (int n = 0; n < 4; ++n) {
      const int rb = (wc << 6) + (n << 4) + lr;
      bfr[n] = *(const bf16x8*)(base + 12288 + rb * 64 + SWZ(rb));
    }
    lgkm0_sb();
    __builtin_amdgcn_s_setprio(1);
#pragma unroll
    for (int m = 0; m < 2; ++m)
#pragma unroll
      for (int n = 0; n < 4; ++n)
        acc2[m][n] = __builtin_amdgcn_mfma_f32_16x16x32_bf16(af[m], bfr[n], acc2[m][n], 0, 0, 0);
    __builtin_amdgcn_s_setprio(0);
    __builtin_amdgcn_sched_barrier(0);
    // phase 3: B3 (ya-pre); need kt's B3 -> allow kt+1's A,B1,B2 (5)
    if (ktn < nkt) waitvm<5>();
    else waitvm<0>();
    barrier_mem();
    if (ktn < nkt) STB(nb, ktn, gB3, 20480);
#pragma unroll
    for (int n = 0; n < 4; ++n) {
      const int rb = (wc << 6) + (n << 4) + lr;
      bfr[n] = *(const bf16x8*)(base + 20480 + rb * 64 + SWZ(rb));
    }
    lgkm0_sb();
    __builtin_amdgcn_s_setprio(1);
#pragma unroll
    for (int m = 0; m < 2; ++m)
#pragma unroll
      for (int n = 0; n < 4; ++n)
        acc3[m][n] = __builtin_amdgcn_mfma_f32_16x16x32_bf16(af[m], bfr[n], acc3[m][n], 0, 0, 0);
    __builtin_amdgcn_s_setprio(0);
    __builtin_amdgcn_sched_barrier(0);
  }

  const int orow = row0 + (wr << 5) + (ks << 2);
  const int ocol = col0 + (wc << 6) + lr;
#pragma unroll
  for (int m = 0; m < 2; ++m) {
#pragma unroll
    for (int n = 0; n < 4; ++n) {
      const int c = ocol + (n << 4);
      const float bv1 = b1[c], bv2 = b2[c], bv3 = b3[c];
#pragma unroll
      for (int i = 0; i < 4; ++i) {
        const int r = orow + (m << 4) + i;
        const size_t idx = (size_t)r * N + c;
        zout[idx] = f2bf((acc1[m][n][i] + bv1) * silu_f(acc2[m][n][i] + bv2));
        yaout[idx] = f2bf(acc3[m][n][i] + bv3);
      }
    }
  }
#undef STA
#undef STB
}

// ---------------- 4-wave single GEMM -------------------------------------------
// MODE 0: out_f32 = v ;  MODE 3: out_f32 += v*silu(aux bf16) ;  MODE 4: out_f32 += v
template <int MODE, int BM, int BN, int WM, int WN, int NBUF>
__global__ __launch_bounds__(256, 2) void gemm_k(const short* __restrict__ A,
                                                 const short* __restrict__ BT,
                                                 const float* __restrict__ bias,
                                                 const short* __restrict__ aux,
                                                 void* __restrict__ outp,
                                                 int N, int K) {
  constexpr int MF = WM / 16, NF = WN / 16;
  constexpr int NWN = BN / WN;
  constexpr int PBB = (BM + BN) * 64;
  constexpr int DEPTH = NBUF - 1;
  constexpr int L = (BM + BN) / 64;
  static_assert((BM / WM) * (BN / WN) == 4, "4 waves");
  __shared__ __align__(16) char lds[NBUF * PBB];
  int bx, by;
  tile_map<4096 / BM>(&bx, &by);
  const int row0 = by * BM, col0 = bx * BN;
  const int t = threadIdx.x, w = t >> 6, lane = t & 63;
  const int wr = w / NWN, wc = w % NWN;
  f32x4 acc[MF][NF] = {};

  const int sslot = (t & 3) ^ ((t >> 3) & 3);
  const char* gA0 = (const char*)A + ((size_t)(row0 + (t >> 2)) * K) * 2 + sslot * 16;
  const char* gB0 = (const char*)BT + ((size_t)(col0 + (t >> 2)) * K) * 2 + sslot * 16;
  const size_t ccstep = (size_t)K * 128;
  const int wb = w << 10;
  const int lr = lane & 15, ks = lane >> 4;

  const int NIT = K >> 5;
  auto stage = [&](int buf, int it) {
    char* dst = lds + buf * PBB;
    const size_t io = (size_t)it * 64;
#pragma unroll
    for (int cc = 0; cc < BM / 64; ++cc)
      async16(gA0 + io + cc * ccstep, dst + cc * 4096 + wb);
#pragma unroll
    for (int cc = 0; cc < BN / 64; ++cc)
      async16(gB0 + io + cc * ccstep, dst + BM * 64 + cc * 4096 + wb);
  };

#pragma unroll
  for (int pit = 0; pit < DEPTH; ++pit) stage(pit, pit);

  for (int it = 0; it < NIT; ++it) {
    const int rem = NIT - it;
    if (rem >= DEPTH + 1) waitvm<L * (DEPTH - 1)>();
    else if (rem >= 2) waitvm<L>();
    else waitvm<0>();
    barrier_mem();
    if (it + DEPTH < NIT) stage((it + DEPTH) % NBUF, it + DEPTH);
    const char* base = lds + (it % NBUF) * PBB;
    bf16x8 af[MF], bfr[NF];
#pragma unroll
    for (int m = 0; m < MF; ++m) {
      const int r = wr * WM + m * 16 + lr;
      af[m] = *(const bf16x8*)(base + r * 64 + SWZ(r));
    }
#pragma unroll
    for (int n = 0; n < NF; ++n) {
      const int r = wc * WN + n * 16 + lr;
      bfr[n] = *(const bf16x8*)(base + BM * 64 + r * 64 + SWZ(r));
    }
    lgkm0_sb();
    __builtin_amdgcn_s_setprio(1);
#pragma unroll
    for (int m = 0; m < MF; ++m)
#pragma unroll
      for (int n = 0; n < NF; ++n)
        acc[m][n] = __builtin_amdgcn_mfma_f32_16x16x32_bf16(af[m], bfr[n], acc[m][n], 0, 0, 0);
    __builtin_amdgcn_s_setprio(0);
    __builtin_amdgcn_sched_barrier(0);
  }

  const int orow = row0 + wr * WM + (ks << 2);
  const int ocol = col0 + wc * WN + lr;
#pragma unroll
  for (int m = 0; m < MF; ++m) {
#pragma unroll
    for (int n = 0; n < NF; ++n) {
      const int c = ocol + (n << 4);
      const float bv = bias[c];
#pragma unroll
      for (int i = 0; i < 4; ++i) {
        const int r = orow + (m << 4) + i;
        const size_t idx = (size_t)r * N + c;
        float v = acc[m][n][i] + bv;
        if (MODE == 0) ((float*)outp)[idx] = v;
        else if (MODE == 3) ((float*)outp)[idx] += v * silu_f(bf2f(aux[idx]));
        else ((float*)outp)[idx] += v;
      }
    }
  }
}

// ------------- transpose-convert: W(R,C) fp32 -> WT(C,R) bf16 ------------------
__global__ __launch_bounds__(256) void transp_k(const float* __restrict__ W,
                                                short* __restrict__ WT,
                                                int R, int C) {
  __shared__ float tile[32][33];
  const size_t moff = (size_t)blockIdx.z * R * C;
  const float* Wp = W + moff;
  short* Tp = WT + moff;
  const int c0 = blockIdx.x << 5, r0 = blockIdx.y << 5;
  const int tx = threadIdx.x, ty = threadIdx.y;
#pragma unroll
  for (int i = 0; i < 4; ++i)
    tile[ty + 8 * i][tx] = Wp[(size_t)(r0 + ty + 8 * i) * C + (c0 + tx)];
  __syncthreads();
#pragma unroll
  for (int i = 0; i < 4; ++i)
    Tp[(size_t)(c0 + ty + 8 * i) * R + (r0 + tx)] = f2bf(tile[tx][ty + 8 * i]);
}

// ------------- embedding with max_norm=1 renorm -------------------------------
__global__ __launch_bounds__(256) void embed_k(const int* __restrict__ tok,
                                               const float* __restrict__ emb,
                                               float* __restrict__ x) {
  const int row = blockIdx.x, t = threadIdx.x, w = t >> 6, lane = t & 63;
  const int token = tok[row];
  float4 v = ((const float4*)(emb + (size_t)token * 1024))[t];
  float ss = v.x * v.x + v.y * v.y + v.z * v.z + v.w * v.w;
#pragma unroll
  for (int off = 32; off; off >>= 1) ss += __shfl_xor(ss, off, 64);
  __shared__ float red[4];
  if (lane == 0) red[w] = ss;
  __syncthreads();
  const float nrm = sqrtf(red[0] + red[1] + red[2] + red[3]);
  const float sc = fminf(1.0f, 1.0f / fmaxf(nrm, 1e-7f));
  v.x *= sc; v.y *= sc; v.z *= sc; v.w *= sc;
  ((float4*)(x + (size_t)row * 1024))[t] = v;
}

// ------------- RMSNorm row kernel (fp32 or bf16 input) -> bf16 out -------------
template <int BF>
__global__ __launch_bounds__(256) void rms_k(const void* __restrict__ xin,
                                             const float* __restrict__ g,
                                             short* __restrict__ o) {
  const int row = blockIdx.x, t = threadIdx.x, w = t >> 6, lane = t & 63;
  float v0, v1, v2, v3;
  if (BF) {
    short4 s = ((const short4*)((const short*)xin + (size_t)row * 1024))[t];
    v0 = bf2f(s.x); v1 = bf2f(s.y); v2 = bf2f(s.z); v3 = bf2f(s.w);
  } else {
    float4 v = ((const float4*)((const float*)xin + (size_t)row * 1024))[t];
    v0 = v.x; v1 = v.y; v2 = v.z; v3 = v.w;
  }
  float ss = v0 * v0 + v1 * v1 + v2 * v2 + v3 * v3;
#pragma unroll
  for (int off = 32; off; off >>= 1) ss += __shfl_xor(ss, off, 64);
  __shared__ float red[4];
  if (lane == 0) red[w] = ss;
  __syncthreads();
  const float sc = rsqrtf((red[0] + red[1] + red[2] + red[3]) * (1.0f / 1024.0f) + 1e-6f);
  float4 gv = ((const float4*)g)[t];
  short4 ov = make_short4(f2bf(v0 * sc * gv.x), f2bf(v1 * sc * gv.y),
                          f2bf(v2 * sc * gv.z), f2bf(v3 * sc * gv.w));
  *(short4*)(o + (size_t)row * 1024 + 4 * t) = ov;
}

// ------------- final LayerNorm: fp32 in -> bf16 out ---------------------------
__global__ __launch_bounds__(256) void ln_k(const float* __restrict__ x,
                                            const float* __restrict__ lw,
                                            const float* __restrict__ lb,
                                            short* __restrict__ o) {
  const int row = blockIdx.x, t = threadIdx.x, w = t >> 6, lane = t & 63;
  float4 v = ((const float4*)(x + (size_t)row * 1024))[t];
  float s1 = v.x + v.y + v.z + v.w;
  float s2 = v.x * v.x + v.y * v.y + v.z * v.z + v.w * v.w;
#pragma unroll
  for (int off = 32; off; off >>= 1) {
    s1 += __shfl_xor(s1, off, 64);
    s2 += __shfl_xor(s2, off, 64);
  }
  __shared__ float red[8];
  if (lane == 0) { red[w] = s1; red[4 + w] = s2; }
  __syncthreads();
  const float mu = (red[0] + red[1] + red[2] + red[3]) * (1.0f / 1024.0f);
  const float ex2 = (red[4] + red[5] + red[6] + red[7]) * (1.0f / 1024.0f);
  const float rs = rsqrtf(ex2 - mu * mu + 1e-5f);
  float4 wv = ((const float4*)lw)[t];
  float4 bv = ((const float4*)lb)[t];
  short4 ov = make_short4(f2bf((v.x - mu) * rs * wv.x + bv.x),
                          f2bf((v.y - mu) * rs * wv.y + bv.y),
                          f2bf((v.z - mu) * rs * wv.z + bv.z),
                          f2bf((v.w - mu) * rs * wv.w + bv.w));
  *(short4*)(o + (size_t)row * 1024 + 4 * t) = ov;
}

// ------------- SConv IIR scan, 2-kernel chunked, bf16 storage ------------------
DEVI void decay_of(int d, float* dr, float* di) {
  const float ang = powf(1e-3f, (float)d * (1.0f / 1023.0f));
  float sn, cs;
  sincosf(ang, &sn, &cs);
  const float mag = expf(1e-5f);
  *dr = mag * cs; *di = mag * sn;
}

__global__ __launch_bounds__(256) void s1_k(const short* __restrict__ z,
                                            float* __restrict__ Er, float* __restrict__ Ei) {
  const int d = (blockIdx.x << 8) + threadIdx.x;
  const int c = blockIdx.y, b = blockIdx.z;
  float dr, di;
  decay_of(d, &dr, &di);
  const short* zp = z + ((size_t)(b * 2048 + c * 64) << 10) + d;
  float sr = 0.0f, si = 0.0f;
  for (int k = 0; k < 64; ++k) {
    float zv = bf2f(zp[(size_t)k << 10]);
    float nr = dr * sr - di * si + zv;
    si = dr * si + di * sr;
    sr = nr;
  }
  const int idx = ((b << 5) + c) * 1024 + d;
  Er[idx] = sr; Ei[idx] = si;
}

// s3 with fused seed-scan: seed = sum_{c'<c} A64^(c-1-c') E[c']
__global__ __launch_bounds__(256) void s3_k(const short* __restrict__ z,
                                            const float* __restrict__ Er,
                                            const float* __restrict__ Ei,
                                            const float* __restrict__ lcre,
                                            const float* __restrict__ lcim,
                                            short* __restrict__ h) {
  const int d = (blockIdx.x << 8) + threadIdx.x;
  const int c = blockIdx.y, b = blockIdx.z;
  float dr, di;
  decay_of(d, &dr, &di);
  float ar = dr, ai = di;
#pragma unroll
  for (int q = 0; q < 6; ++q) { float nr = ar * ar - ai * ai; ai = 2.0f * ar * ai; ar = nr; }
  float sr = 0.0f, si = 0.0f;
  for (int cc = 0; cc < c; ++cc) {
    const int eidx = ((b << 5) + cc) * 1024 + d;
    const float er = Er[eidx], ei = Ei[eidx];
    const float nr = ar * sr - ai * si + er;
    si = ar * si + ai * sr + ei;
    sr = nr;
  }
  float wr = 1.0f, wi = 0.0f, br = ar, bi = ai;
  int e = c;
  while (e) {
    if (e & 1) { float nr = wr * br - wi * bi; wi = wr * bi + wi * br; wr = nr; }
    float nb = br * br - bi * bi; bi = 2.0f * br * bi; br = nb;
    e >>= 1;
  }
  { float nr = wr * dr - wi * di; wi = wr * di + wi * dr; wr = nr; }
  const float lr_ = lcre[d], li_ = lcim[d];
  const size_t base = ((size_t)(b * 2048 + c * 64) << 10) + d;
  for (int k = 0; k < 64; ++k) {
    const float zv = bf2f(z[base + ((size_t)k << 10)]);
    const float nr = dr * sr - di * si + zv;
    si = dr * si + di * sr;
    sr = nr;
    h[base + ((size_t)k << 10)] = f2bf(sr + lr_ * wr - li_ * wi);
    const float nw = wr * dr - wi * di;
    wi = wr * di + wi * dr;
    wr = nw;
  }
}

extern "C" void kernel_launch(void* const* d_in, const int* in_sizes, int n_in,
                              void* d_out, int out_size, void* d_ws, size_t ws_size,
                              hipStream_t stream) {
  const int* tokens = (const int*)d_in[0];
  const float* emb = (const float*)d_in[1];
  const float* Wz = (const float*)d_in[2];
  const float* bz = (const float*)d_in[3];
  const float* Wza = (const float*)d_in[4];
  const float* bza = (const float*)d_in[5];
  const float* Wy = (const float*)d_in[6];
  const float* by = (const float*)d_in[7];
  const float* Wya = (const float*)d_in[8];
  const float* bya = (const float*)d_in[9];
  const float* lc_re = (const float*)d_in[10];
  const float* lc_im = (const float*)d_in[11];
  const float* g_in = (const float*)d_in[12];
  const float* g_sc = (const float*)d_in[13];
  const float* g_ffn = (const float*)d_in[14];
  const float* Wf = (const float*)d_in[15];
  const float* bf = (const float*)d_in[16];
  const float* Wfa = (const float*)d_in[17];
  const float* bfa = (const float*)d_in[18];
  const float* Wfo = (const float*)d_in[19];
  const float* bfo = (const float*)d_in[20];
  const float* ln_w = (const float*)d_in[21];
  const float* ln_b = (const float*)d_in[22];
  const float* Wout = (const float*)d_in[23];
  const float* bout = (const float*)d_in[24];

  char* p = (char*)d_ws;
  float* xb = (float*)p;   p += (size_t)4096 * 1024 * 4;
  short* zb = (short*)p;   p += (size_t)4096 * 1024 * 2;
  short* hb = (short*)p;   p += (size_t)4096 * 1024 * 2;
  short* yab = (short*)p;  p += (size_t)4096 * 1024 * 2;
  float* Er = (float*)p;   p += (size_t)2 * 32 * 1024 * 4;
  float* Ei = (float*)p;   p += (size_t)2 * 32 * 1024 * 4;
  short* xnb = (short*)p;  p += (size_t)4096 * 1024 * 2;
  short* hnb = (short*)p;  p += (size_t)4096 * 1024 * 2;
  short* gb = (short*)p;   p += (size_t)4096 * 4096 * 2;
  short* WzT = (short*)p;  p += (size_t)4 * 1024 * 1024 * 2;
  short* WzaT = (short*)p; p += (size_t)4 * 1024 * 1024 * 2;
  short* WyT = (short*)p;  p += (size_t)4 * 1024 * 1024 * 2;
  short* WyaT = (short*)p; p += (size_t)4 * 1024 * 1024 * 2;
  short* WfT = (short*)p;  p += (size_t)4 * 1024 * 4096 * 2;
  short* WfaT = (short*)p; p += (size_t)4 * 1024 * 4096 * 2;
  short* WfoT = (short*)p; p += (size_t)4 * 1024 * 4096 * 2;
  short* WoutT = (short*)p; p += (size_t)32000 * 1024 * 2;

  const dim3 tb(32, 8);
  transp_k<<<dim3(32, 32, 4), tb, 0, stream>>>(Wz, WzT, 1024, 1024);
  transp_k<<<dim3(32, 32, 4), tb, 0, stream>>>(Wza, WzaT, 1024, 1024);
  transp_k<<<dim3(32, 32, 4), tb, 0, stream>>>(Wy, WyT, 1024, 1024);
  transp_k<<<dim3(32, 32, 4), tb, 0, stream>>>(Wya, WyaT, 1024, 1024);
  transp_k<<<dim3(128, 32, 4), tb, 0, stream>>>(Wf, WfT, 1024, 4096);
  transp_k<<<dim3(128, 32, 4), tb, 0, stream>>>(Wfa, WfaT, 1024, 4096);
  transp_k<<<dim3(32, 128, 4), tb, 0, stream>>>(Wfo, WfoT, 4096, 1024);
  transp_k<<<dim3(1000, 32, 1), tb, 0, stream>>>(Wout, WoutT, 1024, 32000);

  embed_k<<<4096, 256, 0, stream>>>(tokens, emb, xb);

  for (int i = 0; i < 4; ++i) {
    const size_t dd = (size_t)i * 1024 * 1024;
    const size_t dv = (size_t)i * 1024;
    const size_t dw = (size_t)i * 1024 * 4096;
    const size_t df = (size_t)i * 4096;
    rms_k<0><<<4096, 256, 0, stream>>>(xb, g_sc + dv, xnb);
    // z = (xn@Wz+bz)*silu(xn@Wza+bza); yapre = xn@Wya+bya   [triple, counted vmcnt]
    triple_k<<<512, 256, 0, stream>>>(xnb, WzT + dd, WzaT + dd, WyaT + dd,
                                      bz + dv, bza + dv, bya + dv, zb, yab, 1024, 1024);
    s1_k<<<dim3(4, 32, 2), 256, 0, stream>>>(zb, Er, Ei);
    s3_k<<<dim3(4, 32, 2), 256, 0, stream>>>(zb, Er, Ei, lc_re + dv, lc_im + dv, hb);
    rms_k<1><<<4096, 256, 0, stream>>>(hb, g_in + dv, hnb);
    // x += (hn@Wy+by) * silu(yapre)
    gemm_k<3, 64, 128, 32, 64, 3><<<512, 256, 0, stream>>>(
        hnb, WyT + dd, by + dv, yab, xb, 1024, 1024);
    rms_k<0><<<4096, 256, 0, stream>>>(xb, g_ffn + dv, xnb);
    // g = (xn@Wf+bf) * silu(xn@Wfa+bfa) -> bf16   [dual v3: 128x128, 2 blk/CU]
    dual_k<<<1024, 256, 0, stream>>>(xnb, WfT + dw, WfaT + dw, bf + df, bfa + df,
                                     gb, 4096, 1024);
    // x += g@Wfo + bfo
    gemm_k<4, 64, 128, 32, 64, 4><<<512, 256, 0, stream>>>(
        gb, WfoT + dw, bfo + dv, nullptr, xb, 1024, 4096);
  }

  ln_k<<<4096, 256, 0, stream>>>(xb, ln_w, ln_b, xnb);
  // vocab: voc v3 256x128, 3-ring 72KB, 2 blocks/CU, counted vmcnt(3)
  voc_k<<<4000, 512, 0, stream>>>(xnb, WoutT, bout, (float*)d_out, 32000, 1024);

  (void)in_sizes; (void)n_in; (void)out_size; (void)ws_size;
}

// Round 10
// 1566.018 us; speedup vs baseline: 1.0169x; 1.0169x over previous
//
#include <hip/hip_runtime.h>
#include <math.h>

typedef __attribute__((ext_vector_type(8))) short bf16x8;
typedef __attribute__((ext_vector_type(4))) float f32x4;

#define DEVI __device__ __forceinline__

DEVI short f2bf(float f) {
  unsigned u = __builtin_bit_cast(unsigned, f);
  return (short)((u + 0x7fffu + ((u >> 16) & 1u)) >> 16);
}
DEVI float bf2f(short s) {
  unsigned u = ((unsigned)(unsigned short)s) << 16;
  return __builtin_bit_cast(float, u);
}

DEVI float silu_f(float v) { return v / (1.0f + expf(-v)); }

DEVI void async16(const void* g, void* l) {
  __builtin_amdgcn_global_load_lds(
      (const __attribute__((address_space(1))) void*)g,
      (__attribute__((address_space(3))) void*)l, 16, 0, 0);
}

template <int N>
DEVI void waitvm() { asm volatile("s_waitcnt vmcnt(%0)" ::"i"(N) : "memory"); }
DEVI void barrier_mem() { asm volatile("s_barrier" ::: "memory"); }
DEVI void lgkm0_sb() {
  asm volatile("s_waitcnt lgkmcnt(0)" ::: "memory");
  __builtin_amdgcn_sched_barrier(0);
}

// bijective XCD swizzle (nwg % 8 == 0 always here), M-tile fastest within XCD chunk
template <int NROWT>
DEVI void tile_map(int* bx, int* by) {
  const int nwg = gridDim.x;
  const int lin = blockIdx.x;
  const int q = nwg >> 3;
  const int wgid = (lin & 7) * q + (lin >> 3);
  *by = wgid % NROWT;
  *bx = wgid / NROWT;
}

// LDS: rows of 64B (32 bf16 k-slice), 4x16B slots, slot XOR-swizzled by (row>>1)&3.
// global_load_lds writes linearly -> pre-swizzle the per-lane GLOBAL source slot
// (rule #21). Verified R3-R9: SQ_LDS_BANK_CONFLICT == 0.
#define SWZ(r) ((ks ^ (((r) >> 1) & 3)) << 4)

// =============== vocab GEMM v4: 256x128 block, wave 128x64 (43.7 FLOP/LDS-B) ===
// 256 thr, 4 waves (2M x 2N). BK=32, 2-ring 48KB -> 2 blocks/CU. Counted
// vmcnt(6): next tile always in flight; stage(kt+2) issued before MFMA.
__global__ __launch_bounds__(256, 2) void voc_k(const short* __restrict__ A,
                                                const short* __restrict__ BT,
                                                const float* __restrict__ bias,
                                                float* __restrict__ outp,
                                                int N, int K) {
  __shared__ __align__(16) char lds[2 * 24576];
  int bx, by;
  tile_map<16>(&bx, &by);
  const int row0 = by << 8, col0 = bx << 7;
  const int t = threadIdx.x, w = t >> 6, lane = t & 63;
  const int wm = w >> 1, wn = w & 1;
  const int lr = lane & 15, ks = lane >> 4;
  f32x4 acc[8][4] = {};

  const int sslot = (t & 3) ^ ((t >> 3) & 3);
  const char* gA = (const char*)A + ((size_t)(row0 + (t >> 2)) * K) * 2 + sslot * 16;
  const char* gB = (const char*)BT + ((size_t)(col0 + (t >> 2)) * K) * 2 + sslot * 16;
  const size_t cstep = (size_t)K << 7;  // 64 rows forward (256 thr cover 64 rows)
  const int t16 = t << 4;
  const int nkt = K >> 5;

  // buffer 24KB: A rows 0..255 linear @0 (4 chunks of 64 rows); B rows 0..127 @16384
#define SV(nb, kt)                                                            \
  {                                                                           \
    const size_t co = (size_t)(kt) << 6;                                      \
    async16(gA + co, (nb) + t16);                                             \
    async16(gA + cstep + co, (nb) + 4096 + t16);                              \
    async16(gA + 2 * cstep + co, (nb) + 8192 + t16);                          \
    async16(gA + 3 * cstep + co, (nb) + 12288 + t16);                         \
    async16(gB + co, (nb) + 16384 + t16);                                     \
    async16(gB + cstep + co, (nb) + 20480 + t16);                             \
  }

  SV(lds, 0);
  SV(lds + 24576, 1);

  for (int kt = 0; kt < nkt; ++kt) {
    char* buf = lds + (kt & 1) * 24576;
    if (kt + 1 < nkt) waitvm<6>();  // tile kt landed; kt+1 (6 loads) in flight
    else waitvm<0>();
    barrier_mem();                  // collective: tile kt visible to all waves
    bf16x8 af[8], bfr[4];
#pragma unroll
    for (int m = 0; m < 8; ++m) {
      const int r = (wm << 7) + (m << 4) + lr;
      af[m] = *(const bf16x8*)(buf + r * 64 + SWZ(r));
    }
#pragma unroll
    for (int n = 0; n < 4; ++n) {
      const int rb = (wn << 6) + (n << 4) + lr;
      bfr[n] = *(const bf16x8*)(buf + 16384 + rb * 64 + SWZ(rb));
    }
    lgkm0_sb();
    barrier_mem();                  // all waves done reading buf -> safe to overwrite
    if (kt + 2 < nkt) SV(buf, kt + 2);
    __builtin_amdgcn_s_setprio(1);
#pragma unroll
    for (int m = 0; m < 8; ++m)
#pragma unroll
      for (int n = 0; n < 4; ++n)
        acc[m][n] = __builtin_amdgcn_mfma_f32_16x16x32_bf16(af[m], bfr[n], acc[m][n], 0, 0, 0);
    __builtin_amdgcn_s_setprio(0);
    __builtin_amdgcn_sched_barrier(0);
  }

  const int orow = row0 + (wm << 7) + (ks << 2);
  const int ocol = col0 + (wn << 6) + lr;
#pragma unroll
  for (int m = 0; m < 8; ++m) {
#pragma unroll
    for (int n = 0; n < 4; ++n) {
      const int c = ocol + (n << 4);
      const float bv = bias[c];
#pragma unroll
      for (int i = 0; i < 4; ++i) {
        const int r = orow + (m << 4) + i;
        outp[(size_t)r * N + c] = acc[m][n][i] + bv;
      }
    }
  }
#undef SV
}

// =============== dual GEMM (R8 version): 256x128, BK=32, 4-ring, depth-3 ======
// bf16 out = (A@B1+b1)*silu(A@B2+b2). 512 thr, 8 waves (4M x 2N), wave 64x64 dual.
__global__ __launch_bounds__(512, 1) void dual8_k(const short* __restrict__ A,
                                                  const short* __restrict__ BT1,
                                                  const short* __restrict__ BT2,
                                                  const float* __restrict__ bias1,
                                                  const float* __restrict__ bias2,
                                                  short* __restrict__ outp,
                                                  int N, int K) {
  __shared__ __align__(16) char lds[4 * 32768];
  int bx, by;
  tile_map<16>(&bx, &by);
  const int row0 = by << 8, col0 = bx << 7;
  const int t = threadIdx.x, w = t >> 6, lane = t & 63;
  const int wm = w >> 1, wn = w & 1;
  const int lr = lane & 15, ks = lane >> 4;
  f32x4 acc1[4][4] = {}, acc2[4][4] = {};

  const int sslot = (t & 3) ^ ((t >> 3) & 3);
  const char* gA = (const char*)A + ((size_t)(row0 + (t >> 2)) * K) * 2 + sslot * 16;
  const char* gB1 = (const char*)BT1 + ((size_t)(col0 + (t >> 2)) * K) * 2 + sslot * 16;
  const char* gB2 = (const char*)BT2 + ((size_t)(col0 + (t >> 2)) * K) * 2 + sslot * 16;
  const size_t cstep = (size_t)K << 8;
  const int t16 = t << 4;
  const int nkt = K >> 5;

#define SAD(nb, kt)                                                           \
  {                                                                           \
    const size_t co = (size_t)(kt) << 6;                                      \
    async16(gA + co, (nb) + t16);                                             \
    async16(gA + cstep + co, (nb) + 8192 + t16);                              \
  }
#define SB1D(nb, kt) async16(gB1 + ((size_t)(kt) << 6), (nb) + 16384 + t16)
#define SB2D(nb, kt) async16(gB2 + ((size_t)(kt) << 6), (nb) + 24576 + t16)

  SAD(lds, 0); SB1D(lds, 0); SB2D(lds, 0);
  SAD(lds + 32768, 1); SB1D(lds + 32768, 1); SB2D(lds + 32768, 1);
  SAD(lds + 65536, 2); SB1D(lds + 65536, 2); SB2D(lds + 65536, 2);

  for (int kt = 0; kt < nkt; ++kt) {
    const char* base = lds + (kt & 3) * 32768;
    char* nb = lds + ((kt + 3) & 3) * 32768;
    const int rem = nkt - kt;
    bf16x8 af[4], bfr[4];
    if (rem > 2) waitvm<8>();
    else if (rem == 2) waitvm<4>();
    else waitvm<0>();
    barrier_mem();
    if (kt + 3 < nkt) SAD(nb, kt + 3);
#pragma unroll
    for (int n = 0; n < 4; ++n) {
      const int rb = (wn << 6) + (n << 4) + lr;
      bfr[n] = *(const bf16x8*)(base + 16384 + rb * 64 + SWZ(rb));
    }
#pragma unroll
    for (int m = 0; m < 4; ++m) {
      const int r = (wm << 6) + (m << 4) + lr;
      af[m] = *(const bf16x8*)(base + r * 64 + SWZ(r));
    }
    lgkm0_sb();
    __builtin_amdgcn_s_setprio(1);
#pragma unroll
    for (int m = 0; m < 4; ++m)
#pragma unroll
      for (int n = 0; n < 4; ++n)
        acc1[m][n] = __builtin_amdgcn_mfma_f32_16x16x32_bf16(af[m], bfr[n], acc1[m][n], 0, 0, 0);
    __builtin_amdgcn_s_setprio(0);
    __builtin_amdgcn_sched_barrier(0);
    barrier_mem();
    if (kt + 3 < nkt) { SB1D(nb, kt + 3); SB2D(nb, kt + 3); }
#pragma unroll
    for (int n = 0; n < 4; ++n) {
      const int rb = (wn << 6) + (n << 4) + lr;
      bfr[n] = *(const bf16x8*)(base + 24576 + rb * 64 + SWZ(rb));
    }
    lgkm0_sb();
    __builtin_amdgcn_s_setprio(1);
#pragma unroll
    for (int m = 0; m < 4; ++m)
#pragma unroll
      for (int n = 0; n < 4; ++n)
        acc2[m][n] = __builtin_amdgcn_mfma_f32_16x16x32_bf16(af[m], bfr[n], acc2[m][n], 0, 0, 0);
    __builtin_amdgcn_s_setprio(0);
    __builtin_amdgcn_sched_barrier(0);
  }

  const int orow = row0 + (wm << 6) + (ks << 2);
  const int ocol = col0 + (wn << 6) + lr;
#pragma unroll
  for (int m = 0; m < 4; ++m) {
#pragma unroll
    for (int n = 0; n < 4; ++n) {
      const int c = ocol + (n << 4);
      const float bv1 = bias1[c], bv2 = bias2[c];
#pragma unroll
      for (int i = 0; i < 4; ++i) {
        const int r = orow + (m << 4) + i;
        outp[(size_t)r * N + c] = f2bf((acc1[m][n][i] + bv1) * silu_f(acc2[m][n][i] + bv2));
      }
    }
  }
#undef SAD
#undef SB1D
#undef SB2D
}

// =============== TRIPLE shared-A GEMM (z, za, ya), counted waits ==============
__global__ __launch_bounds__(256, 2) void triple_k(const short* __restrict__ A,
                                                   const short* __restrict__ BT1,
                                                   const short* __restrict__ BT2,
                                                   const short* __restrict__ BT3,
                                                   const float* __restrict__ b1,
                                                   const float* __restrict__ b2,
                                                   const float* __restrict__ b3,
                                                   short* __restrict__ zout,
                                                   short* __restrict__ yaout,
                                                   int N, int K) {
  constexpr int PBB = 28672;  // A 4K + 3 x B 8K
  __shared__ __align__(16) char lds[2 * PBB];
  int bx, by;
  tile_map<64>(&bx, &by);
  const int row0 = by << 6, col0 = bx << 7;
  const int t = threadIdx.x, w = t >> 6, lane = t & 63;
  const int wr = w >> 1, wc = w & 1;
  const int lr = lane & 15, ks = lane >> 4;
  f32x4 acc1[2][4] = {}, acc2[2][4] = {}, acc3[2][4] = {};

  const int sslot = (t & 3) ^ ((t >> 3) & 3);
  const char* gA = (const char*)A + ((size_t)(row0 + (t >> 2)) * K) * 2 + sslot * 16;
  const size_t brow = ((size_t)(col0 + (t >> 2)) * K) * 2 + sslot * 16;
  const char* gB1 = (const char*)BT1 + brow;
  const char* gB2 = (const char*)BT2 + brow;
  const char* gB3 = (const char*)BT3 + brow;
  const size_t cstep = (size_t)K * 128;
  const int t16 = t << 4;
  const int nkt = K >> 5;

#define STA(nb, kt) async16(gA + (size_t)(kt) * 64, (nb) + t16)
#define STB(nb, kt, gp, off)                                                  \
  {                                                                           \
    const size_t co = (size_t)(kt) * 64;                                      \
    async16((gp) + co, (nb) + (off) + t16);                                   \
    async16((gp) + cstep + co, (nb) + (off) + 4096 + t16);                    \
  }

  { char* nb = lds; STA(nb, 0); STB(nb, 0, gB1, 4096); STB(nb, 0, gB2, 12288); STB(nb, 0, gB3, 20480); }

  for (int kt = 0; kt < nkt; ++kt) {
    const int ktn = kt + 1;
    const char* base = lds + (kt & 1) * PBB;
    char* nb = lds + (ktn & 1) * PBB;
    bf16x8 af[2], bfr[4];
    waitvm<4>();
    barrier_mem();
    if (ktn < nkt) { STA(nb, ktn); STB(nb, ktn, gB1, 4096); }
#pragma unroll
    for (int m = 0; m < 2; ++m) {
      const int r = (wr << 5) + (m << 4) + lr;
      af[m] = *(const bf16x8*)(base + r * 64 + SWZ(r));
    }
#pragma unroll
    for (int n = 0; n < 4; ++n) {
      const int rb = (wc << 6) + (n << 4) + lr;
      bfr[n] = *(const bf16x8*)(base + 4096 + rb * 64 + SWZ(rb));
    }
    lgkm0_sb();
    __builtin_amdgcn_s_setprio(1);
#pragma unroll
    for (int m = 0; m < 2; ++m)
#pragma unroll
      for (int n = 0; n < 4; ++n)
        acc1[m][n] = __builtin_amdgcn_mfma_f32_16x16x32_bf16(af[m], bfr[n], acc1[m][n], 0, 0, 0);
    __builtin_amdgcn_s_setprio(0);
    __builtin_amdgcn_sched_barrier(0);
    if (ktn < nkt) waitvm<5>();
    else waitvm<2>();
    barrier_mem();
    if (ktn < nkt) STB(nb, ktn, gB2, 12288);
#pragma unroll
    for (int n = 0; n < 4; ++n) {
      const int rb = (wc << 6) + (n << 4) + lr;
      bfr[n] = *(const bf16x8*)(base + 12288 + rb * 64 + SWZ(rb));
    }
    lgkm0_sb();
    __builtin_amdgcn_s_setprio(1);
#pragma unroll
    for (int m = 0; m < 2; ++m)
#pragma unroll
      for (int n = 0; n < 4; ++n)
        acc2[m][n] = __builtin_amdgcn_mfma_f32_16x16x32_bf16(af[m], bfr[n], acc2[m][n], 0, 0, 0);
    __builtin_amdgcn_s_setprio(0);
    __builtin_amdgcn_sched_barrier(0);
    if (ktn < nkt) waitvm<5>();
    else waitvm<0>();
    barrier_mem();
    if (ktn < nkt) STB(nb, ktn, gB3, 20480);
#pragma unroll
    for (int n = 0; n < 4; ++n) {
      const int rb = (wc << 6) + (n << 4) + lr;
      bfr[n] = *(const bf16x8*)(base + 20480 + rb * 64 + SWZ(rb));
    }
    lgkm0_sb();
    __builtin_amdgcn_s_setprio(1);
#pragma unroll
    for (int m = 0; m < 2; ++m)
#pragma unroll
      for (int n = 0; n < 4; ++n)
        acc3[m][n] = __builtin_amdgcn_mfma_f32_16x16x32_bf16(af[m], bfr[n], acc3[m][n], 0, 0, 0);
    __builtin_amdgcn_s_setprio(0);
    __builtin_amdgcn_sched_barrier(0);
  }

  const int orow = row0 + (wr << 5) + (ks << 2);
  const int ocol = col0 + (wc << 6) + lr;
#pragma unroll
  for (int m = 0; m < 2; ++m) {
#pragma unroll
    for (int n = 0; n < 4; ++n) {
      const int c = ocol + (n << 4);
      const float bv1 = b1[c], bv2 = b2[c], bv3 = b3[c];
#pragma unroll
      for (int i = 0; i < 4; ++i) {
        const int r = orow + (m << 4) + i;
        const size_t idx = (size_t)r * N + c;
        zout[idx] = f2bf((acc1[m][n][i] + bv1) * silu_f(acc2[m][n][i] + bv2));
        yaout[idx] = f2bf(acc3[m][n][i] + bv3);
      }
    }
  }
#undef STA
#undef STB
}

// ---------------- 4-wave single GEMM -------------------------------------------
// MODE 0: out_f32 = v ;  MODE 3: out_f32 += v*silu(aux bf16) ;  MODE 4: out_f32 += v
template <int MODE, int BM, int BN, int WM, int WN, int NBUF>
__global__ __launch_bounds__(256, 2) void gemm_k(const short* __restrict__ A,
                                                 const short* __restrict__ BT,
                                                 const float* __restrict__ bias,
                                                 const short* __restrict__ aux,
                                                 void* __restrict__ outp,
                                                 int N, int K) {
  constexpr int MF = WM / 16, NF = WN / 16;
  constexpr int NWN = BN / WN;
  constexpr int PBB = (BM + BN) * 64;
  constexpr int DEPTH = NBUF - 1;
  constexpr int L = (BM + BN) / 64;
  static_assert((BM / WM) * (BN / WN) == 4, "4 waves");
  __shared__ __align__(16) char lds[NBUF * PBB];
  int bx, by;
  tile_map<4096 / BM>(&bx, &by);
  const int row0 = by * BM, col0 = bx * BN;
  const int t = threadIdx.x, w = t >> 6, lane = t & 63;
  const int wr = w / NWN, wc = w % NWN;
  f32x4 acc[MF][NF] = {};

  const int sslot = (t & 3) ^ ((t >> 3) & 3);
  const char* gA0 = (const char*)A + ((size_t)(row0 + (t >> 2)) * K) * 2 + sslot * 16;
  const char* gB0 = (const char*)BT + ((size_t)(col0 + (t >> 2)) * K) * 2 + sslot * 16;
  const size_t ccstep = (size_t)K * 128;
  const int wb = w << 10;
  const int lr = lane & 15, ks = lane >> 4;

  const int NIT = K >> 5;
  auto stage = [&](int buf, int it) {
    char* dst = lds + buf * PBB;
    const size_t io = (size_t)it * 64;
#pragma unroll
    for (int cc = 0; cc < BM / 64; ++cc)
      async16(gA0 + io + cc * ccstep, dst + cc * 4096 + wb);
#pragma unroll
    for (int cc = 0; cc < BN / 64; ++cc)
      async16(gB0 + io + cc * ccstep, dst + BM * 64 + cc * 4096 + wb);
  };

#pragma unroll
  for (int pit = 0; pit < DEPTH; ++pit) stage(pit, pit);

  for (int it = 0; it < NIT; ++it) {
    const int rem = NIT - it;
    if (rem >= DEPTH + 1) waitvm<L * (DEPTH - 1)>();
    else if (rem >= 2) waitvm<L>();
    else waitvm<0>();
    barrier_mem();
    if (it + DEPTH < NIT) stage((it + DEPTH) % NBUF, it + DEPTH);
    const char* base = lds + (it % NBUF) * PBB;
    bf16x8 af[MF], bfr[NF];
#pragma unroll
    for (int m = 0; m < MF; ++m) {
      const int r = wr * WM + m * 16 + lr;
      af[m] = *(const bf16x8*)(base + r * 64 + SWZ(r));
    }
#pragma unroll
    for (int n = 0; n < NF; ++n) {
      const int r = wc * WN + n * 16 + lr;
      bfr[n] = *(const bf16x8*)(base + BM * 64 + r * 64 + SWZ(r));
    }
    lgkm0_sb();
    __builtin_amdgcn_s_setprio(1);
#pragma unroll
    for (int m = 0; m < MF; ++m)
#pragma unroll
      for (int n = 0; n < NF; ++n)
        acc[m][n] = __builtin_amdgcn_mfma_f32_16x16x32_bf16(af[m], bfr[n], acc[m][n], 0, 0, 0);
    __builtin_amdgcn_s_setprio(0);
    __builtin_amdgcn_sched_barrier(0);
  }

  const int orow = row0 + wr * WM + (ks << 2);
  const int ocol = col0 + wc * WN + lr;
#pragma unroll
  for (int m = 0; m < MF; ++m) {
#pragma unroll
    for (int n = 0; n < NF; ++n) {
      const int c = ocol + (n << 4);
      const float bv = bias[c];
#pragma unroll
      for (int i = 0; i < 4; ++i) {
        const int r = orow + (m << 4) + i;
        const size_t idx = (size_t)r * N + c;
        float v = acc[m][n][i] + bv;
        if (MODE == 0) ((float*)outp)[idx] = v;
        else if (MODE == 3) ((float*)outp)[idx] += v * silu_f(bf2f(aux[idx]));
        else ((float*)outp)[idx] += v;
      }
    }
  }
}

// ------------- transpose-convert: W(R,C) fp32 -> WT(C,R) bf16 ------------------
__global__ __launch_bounds__(256) void transp_k(const float* __restrict__ W,
                                                short* __restrict__ WT,
                                                int R, int C) {
  __shared__ float tile[32][33];
  const size_t moff = (size_t)blockIdx.z * R * C;
  const float* Wp = W + moff;
  short* Tp = WT + moff;
  const int c0 = blockIdx.x << 5, r0 = blockIdx.y << 5;
  const int tx = threadIdx.x, ty = threadIdx.y;
#pragma unroll
  for (int i = 0; i < 4; ++i)
    tile[ty + 8 * i][tx] = Wp[(size_t)(r0 + ty + 8 * i) * C + (c0 + tx)];
  __syncthreads();
#pragma unroll
  for (int i = 0; i < 4; ++i)
    Tp[(size_t)(c0 + ty + 8 * i) * R + (r0 + tx)] = f2bf(tile[tx][ty + 8 * i]);
}

// ------------- embedding with max_norm=1 renorm -------------------------------
__global__ __launch_bounds__(256) void embed_k(const int* __restrict__ tok,
                                               const float* __restrict__ emb,
                                               float* __restrict__ x) {
  const int row = blockIdx.x, t = threadIdx.x, w = t >> 6, lane = t & 63;
  const int token = tok[row];
  float4 v = ((const float4*)(emb + (size_t)token * 1024))[t];
  float ss = v.x * v.x + v.y * v.y + v.z * v.z + v.w * v.w;
#pragma unroll
  for (int off = 32; off; off >>= 1) ss += __shfl_xor(ss, off, 64);
  __shared__ float red[4];
  if (lane == 0) red[w] = ss;
  __syncthreads();
  const float nrm = sqrtf(red[0] + red[1] + red[2] + red[3]);
  const float sc = fminf(1.0f, 1.0f / fmaxf(nrm, 1e-7f));
  v.x *= sc; v.y *= sc; v.z *= sc; v.w *= sc;
  ((float4*)(x + (size_t)row * 1024))[t] = v;
}

// ------------- RMSNorm row kernel (fp32 or bf16 input) -> bf16 out -------------
template <int BF>
__global__ __launch_bounds__(256) void rms_k(const void* __restrict__ xin,
                                             const float* __restrict__ g,
                                             short* __restrict__ o) {
  const int row = blockIdx.x, t = threadIdx.x, w = t >> 6, lane = t & 63;
  float v0, v1, v2, v3;
  if (BF) {
    short4 s = ((const short4*)((const short*)xin + (size_t)row * 1024))[t];
    v0 = bf2f(s.x); v1 = bf2f(s.y); v2 = bf2f(s.z); v3 = bf2f(s.w);
  } else {
    float4 v = ((const float4*)((const float*)xin + (size_t)row * 1024))[t];
    v0 = v.x; v1 = v.y; v2 = v.z; v3 = v.w;
  }
  float ss = v0 * v0 + v1 * v1 + v2 * v2 + v3 * v3;
#pragma unroll
  for (int off = 32; off; off >>= 1) ss += __shfl_xor(ss, off, 64);
  __shared__ float red[4];
  if (lane == 0) red[w] = ss;
  __syncthreads();
  const float sc = rsqrtf((red[0] + red[1] + red[2] + red[3]) * (1.0f / 1024.0f) + 1e-6f);
  float4 gv = ((const float4*)g)[t];
  short4 ov = make_short4(f2bf(v0 * sc * gv.x), f2bf(v1 * sc * gv.y),
                          f2bf(v2 * sc * gv.z), f2bf(v3 * sc * gv.w));
  *(short4*)(o + (size_t)row * 1024 + 4 * t) = ov;
}

// ------------- final LayerNorm: fp32 in -> bf16 out ---------------------------
__global__ __launch_bounds__(256) void ln_k(const float* __restrict__ x,
                                            const float* __restrict__ lw,
                                            const float* __restrict__ lb,
                                            short* __restrict__ o) {
  const int row = blockIdx.x, t = threadIdx.x, w = t >> 6, lane = t & 63;
  float4 v = ((const float4*)(x + (size_t)row * 1024))[t];
  float s1 = v.x + v.y + v.z + v.w;
  float s2 = v.x * v.x + v.y * v.y + v.z * v.z + v.w * v.w;
#pragma unroll
  for (int off = 32; off; off >>= 1) {
    s1 += __shfl_xor(s1, off, 64);
    s2 += __shfl_xor(s2, off, 64);
  }
  __shared__ float red[8];
  if (lane == 0) { red[w] = s1; red[4 + w] = s2; }
  __syncthreads();
  const float mu = (red[0] + red[1] + red[2] + red[3]) * (1.0f / 1024.0f);
  const float ex2 = (red[4] + red[5] + red[6] + red[7]) * (1.0f / 1024.0f);
  const float rs = rsqrtf(ex2 - mu * mu + 1e-5f);
  float4 wv = ((const float4*)lw)[t];
  float4 bv = ((const float4*)lb)[t];
  short4 ov = make_short4(f2bf((v.x - mu) * rs * wv.x + bv.x),
                          f2bf((v.y - mu) * rs * wv.y + bv.y),
                          f2bf((v.z - mu) * rs * wv.z + bv.z),
                          f2bf((v.w - mu) * rs * wv.w + bv.w));
  *(short4*)(o + (size_t)row * 1024 + 4 * t) = ov;
}

// ------------- SConv IIR scan, 2-kernel chunked, bf16 storage ------------------
DEVI void decay_of(int d, float* dr, float* di) {
  const float ang = powf(1e-3f, (float)d * (1.0f / 1023.0f));
  float sn, cs;
  sincosf(ang, &sn, &cs);
  const float mag = expf(1e-5f);
  *dr = mag * cs; *di = mag * sn;
}

__global__ __launch_bounds__(256) void s1_k(const short* __restrict__ z,
                                            float* __restrict__ Er, float* __restrict__ Ei) {
  const int d = (blockIdx.x << 8) + threadIdx.x;
  const int c = blockIdx.y, b = blockIdx.z;
  float dr, di;
  decay_of(d, &dr, &di);
  const short* zp = z + ((size_t)(b * 2048 + c * 64) << 10) + d;
  float sr = 0.0f, si = 0.0f;
  for (int k = 0; k < 64; ++k) {
    float zv = bf2f(zp[(size_t)k << 10]);
    float nr = dr * sr - di * si + zv;
    si = dr * si + di * sr;
    sr = nr;
  }
  const int idx = ((b << 5) + c) * 1024 + d;
  Er[idx] = sr; Ei[idx] = si;
}

// s3 with fused seed-scan: seed = sum_{c'<c} A64^(c-1-c') E[c']
__global__ __launch_bounds__(256) void s3_k(const short* __restrict__ z,
                                            const float* __restrict__ Er,
                                            const float* __restrict__ Ei,
                                            const float* __restrict__ lcre,
                                            const float* __restrict__ lcim,
                                            short* __restrict__ h) {
  const int d = (blockIdx.x << 8) + threadIdx.x;
  const int c = blockIdx.y, b = blockIdx.z;
  float dr, di;
  decay_of(d, &dr, &di);
  float ar = dr, ai = di;
#pragma unroll
  for (int q = 0; q < 6; ++q) { float nr = ar * ar - ai * ai; ai = 2.0f * ar * ai; ar = nr; }
  float sr = 0.0f, si = 0.0f;
  for (int cc = 0; cc < c; ++cc) {
    const int eidx = ((b << 5) + cc) * 1024 + d;
    const float er = Er[eidx], ei = Ei[eidx];
    const float nr = ar * sr - ai * si + er;
    si = ar * si + ai * sr + ei;
    sr = nr;
  }
  float wr = 1.0f, wi = 0.0f, br = ar, bi = ai;
  int e = c;
  while (e) {
    if (e & 1) { float nr = wr * br - wi * bi; wi = wr * bi + wi * br; wr = nr; }
    float nb = br * br - bi * bi; bi = 2.0f * br * bi; br = nb;
    e >>= 1;
  }
  { float nr = wr * dr - wi * di; wi = wr * di + wi * dr; wr = nr; }
  const float lr_ = lcre[d], li_ = lcim[d];
  const size_t base = ((size_t)(b * 2048 + c * 64) << 10) + d;
  for (int k = 0; k < 64; ++k) {
    const float zv = bf2f(z[base + ((size_t)k << 10)]);
    const float nr = dr * sr - di * si + zv;
    si = dr * si + di * sr;
    sr = nr;
    h[base + ((size_t)k << 10)] = f2bf(sr + lr_ * wr - li_ * wi);
    const float nw = wr * dr - wi * di;
    wi = wr * di + wi * dr;
    wr = nw;
  }
}

extern "C" void kernel_launch(void* const* d_in, const int* in_sizes, int n_in,
                              void* d_out, int out_size, void* d_ws, size_t ws_size,
                              hipStream_t stream) {
  const int* tokens = (const int*)d_in[0];
  const float* emb = (const float*)d_in[1];
  const float* Wz = (const float*)d_in[2];
  const float* bz = (const float*)d_in[3];
  const float* Wza = (const float*)d_in[4];
  const float* bza = (const float*)d_in[5];
  const float* Wy = (const float*)d_in[6];
  const float* by = (const float*)d_in[7];
  const float* Wya = (const float*)d_in[8];
  const float* bya = (const float*)d_in[9];
  const float* lc_re = (const float*)d_in[10];
  const float* lc_im = (const float*)d_in[11];
  const float* g_in = (const float*)d_in[12];
  const float* g_sc = (const float*)d_in[13];
  const float* g_ffn = (const float*)d_in[14];
  const float* Wf = (const float*)d_in[15];
  const float* bf = (const float*)d_in[16];
  const float* Wfa = (const float*)d_in[17];
  const float* bfa = (const float*)d_in[18];
  const float* Wfo = (const float*)d_in[19];
  const float* bfo = (const float*)d_in[20];
  const float* ln_w = (const float*)d_in[21];
  const float* ln_b = (const float*)d_in[22];
  const float* Wout = (const float*)d_in[23];
  const float* bout = (const float*)d_in[24];

  char* p = (char*)d_ws;
  float* xb = (float*)p;   p += (size_t)4096 * 1024 * 4;
  short* zb = (short*)p;   p += (size_t)4096 * 1024 * 2;
  short* hb = (short*)p;   p += (size_t)4096 * 1024 * 2;
  short* yab = (short*)p;  p += (size_t)4096 * 1024 * 2;
  float* Er = (float*)p;   p += (size_t)2 * 32 * 1024 * 4;
  float* Ei = (float*)p;   p += (size_t)2 * 32 * 1024 * 4;
  short* xnb = (short*)p;  p += (size_t)4096 * 1024 * 2;
  short* hnb = (short*)p;  p += (size_t)4096 * 1024 * 2;
  short* gb = (short*)p;   p += (size_t)4096 * 4096 * 2;
  short* WzT = (short*)p;  p += (size_t)4 * 1024 * 1024 * 2;
  short* WzaT = (short*)p; p += (size_t)4 * 1024 * 1024 * 2;
  short* WyT = (short*)p;  p += (size_t)4 * 1024 * 1024 * 2;
  short* WyaT = (short*)p; p += (size_t)4 * 1024 * 1024 * 2;
  short* WfT = (short*)p;  p += (size_t)4 * 1024 * 4096 * 2;
  short* WfaT = (short*)p; p += (size_t)4 * 1024 * 4096 * 2;
  short* WfoT = (short*)p; p += (size_t)4 * 1024 * 4096 * 2;
  short* WoutT = (short*)p; p += (size_t)32000 * 1024 * 2;

  const dim3 tb(32, 8);
  transp_k<<<dim3(32, 32, 4), tb, 0, stream>>>(Wz, WzT, 1024, 1024);
  transp_k<<<dim3(32, 32, 4), tb, 0, stream>>>(Wza, WzaT, 1024, 1024);
  transp_k<<<dim3(32, 32, 4), tb, 0, stream>>>(Wy, WyT, 1024, 1024);
  transp_k<<<dim3(32, 32, 4), tb, 0, stream>>>(Wya, WyaT, 1024, 1024);
  transp_k<<<dim3(128, 32, 4), tb, 0, stream>>>(Wf, WfT, 1024, 4096);
  transp_k<<<dim3(128, 32, 4), tb, 0, stream>>>(Wfa, WfaT, 1024, 4096);
  transp_k<<<dim3(32, 128, 4), tb, 0, stream>>>(Wfo, WfoT, 4096, 1024);
  transp_k<<<dim3(1000, 32, 1), tb, 0, stream>>>(Wout, WoutT, 1024, 32000);

  embed_k<<<4096, 256, 0, stream>>>(tokens, emb, xb);

  for (int i = 0; i < 4; ++i) {
    const size_t dd = (size_t)i * 1024 * 1024;
    const size_t dv = (size_t)i * 1024;
    const size_t dw = (size_t)i * 1024 * 4096;
    const size_t df = (size_t)i * 4096;
    rms_k<0><<<4096, 256, 0, stream>>>(xb, g_sc + dv, xnb);
    // z = (xn@Wz+bz)*silu(xn@Wza+bza); yapre = xn@Wya+bya   [triple, counted vmcnt]
    triple_k<<<512, 256, 0, stream>>>(xnb, WzT + dd, WzaT + dd, WyaT + dd,
                                      bz + dv, bza + dv, bya + dv, zb, yab, 1024, 1024);
    s1_k<<<dim3(4, 32, 2), 256, 0, stream>>>(zb, Er, Ei);
    s3_k<<<dim3(4, 32, 2), 256, 0, stream>>>(zb, Er, Ei, lc_re + dv, lc_im + dv, hb);
    rms_k<1><<<4096, 256, 0, stream>>>(hb, g_in + dv, hnb);
    // x += (hn@Wy+by) * silu(yapre)
    gemm_k<3, 64, 128, 32, 64, 3><<<512, 256, 0, stream>>>(
        hnb, WyT + dd, by + dv, yab, xb, 1024, 1024);
    rms_k<0><<<4096, 256, 0, stream>>>(xb, g_ffn + dv, xnb);
    // g = (xn@Wf+bf) * silu(xn@Wfa+bfa) -> bf16   [dual8 (R8), depth-3 ring]
    dual8_k<<<512, 512, 0, stream>>>(xnb, WfT + dw, WfaT + dw, bf + df, bfa + df,
                                     gb, 4096, 1024);
    // x += g@Wfo + bfo
    gemm_k<4, 64, 128, 32, 64, 4><<<512, 256, 0, stream>>>(
        gb, WfoT + dw, bfo + dv, nullptr, xb, 1024, 4096);
  }

  ln_k<<<4096, 256, 0, stream>>>(xb, ln_w, ln_b, xnb);
  // vocab: voc v4 — wave 128x64, 2-ring 48KB, 2 blocks/CU, counted vmcnt(6)
  voc_k<<<4000, 256, 0, stream>>>(xnb, WoutT, bout, (float*)d_out, 32000, 1024);

  (void)in_sizes; (void)n_in; (void)out_size; (void)ws_size;
}

// Round 11
// 1508.440 us; speedup vs baseline: 1.0557x; 1.0382x over previous
//
#include <hip/hip_runtime.h>
#include <math.h>

typedef __attribute__((ext_vector_type(8))) short bf16x8;
typedef __attribute__((ext_vector_type(4))) float f32x4;

#define DEVI __device__ __forceinline__

DEVI short f2bf(float f) {
  unsigned u = __builtin_bit_cast(unsigned, f);
  return (short)((u + 0x7fffu + ((u >> 16) & 1u)) >> 16);
}
DEVI float bf2f(short s) {
  unsigned u = ((unsigned)(unsigned short)s) << 16;
  return __builtin_bit_cast(float, u);
}

DEVI float silu_f(float v) { return v / (1.0f + expf(-v)); }

DEVI void async16(const void* g, void* l) {
  __builtin_amdgcn_global_load_lds(
      (const __attribute__((address_space(1))) void*)g,
      (__attribute__((address_space(3))) void*)l, 16, 0, 0);
}

template <int N>
DEVI void waitvm() { asm volatile("s_waitcnt vmcnt(%0)" ::"i"(N) : "memory"); }
DEVI void barrier_mem() { asm volatile("s_barrier" ::: "memory"); }
DEVI void lgkm0_sb() {
  asm volatile("s_waitcnt lgkmcnt(0)" ::: "memory");
  __builtin_amdgcn_sched_barrier(0);
}

// M-partitioned XCD map: XCD i (= blockIdx&7) owns by in [i*NROWT/8, (i+1)*NROWT/8)
// and ALL bx. Per-XCD A working set = NROWT/8 slabs -> L2-resident (no HBM re-fetch
// under the output write stream, which was R10's 590MB FETCH pathology).
// Bijective for nwg%8==0 && NROWT%8==0.
template <int NROWT>
DEVI void tile_map(int* bx, int* by) {
  constexpr int RPX = NROWT / 8;
  const int xcd = blockIdx.x & 7;
  const int idx = blockIdx.x >> 3;
  *by = xcd * RPX + (idx % RPX);
  *bx = idx / RPX;
}

// LDS: rows of 64B (32 bf16 k-slice), 4x16B slots, slot XOR-swizzled by (row>>1)&3.
// global_load_lds writes linearly -> pre-swizzle the per-lane GLOBAL source slot
// (rule #21). Verified R3-R10: SQ_LDS_BANK_CONFLICT == 0.
#define SWZ(r) ((ks ^ (((r) >> 1) & 3)) << 4)

// =============== vocab GEMM v5: 256x128 block, wave 128x64, M-partitioned map ==
// 256 thr, 4 waves (2M x 2N). BK=32, 2-ring 48KB -> 2 blocks/CU. Counted vmcnt(6).
__global__ __launch_bounds__(256, 2) void voc_k(const short* __restrict__ A,
                                                const short* __restrict__ BT,
                                                const float* __restrict__ bias,
                                                float* __restrict__ outp,
                                                int N, int K) {
  __shared__ __align__(16) char lds[2 * 24576];
  int bx, by;
  tile_map<16>(&bx, &by);
  const int row0 = by << 8, col0 = bx << 7;
  const int t = threadIdx.x, w = t >> 6, lane = t & 63;
  const int wm = w >> 1, wn = w & 1;
  const int lr = lane & 15, ks = lane >> 4;
  f32x4 acc[8][4] = {};

  const int sslot = (t & 3) ^ ((t >> 3) & 3);
  const char* gA = (const char*)A + ((size_t)(row0 + (t >> 2)) * K) * 2 + sslot * 16;
  const char* gB = (const char*)BT + ((size_t)(col0 + (t >> 2)) * K) * 2 + sslot * 16;
  const size_t cstep = (size_t)K << 7;  // 64 rows forward (256 thr cover 64 rows)
  const int t16 = t << 4;
  const int nkt = K >> 5;

  // buffer 24KB: A rows 0..255 @0 (4 chunks of 64 rows); B rows 0..127 @16384
#define SV(nb, kt)                                                            \
  {                                                                           \
    const size_t co = (size_t)(kt) << 6;                                      \
    async16(gA + co, (nb) + t16);                                             \
    async16(gA + cstep + co, (nb) + 4096 + t16);                              \
    async16(gA + 2 * cstep + co, (nb) + 8192 + t16);                          \
    async16(gA + 3 * cstep + co, (nb) + 12288 + t16);                         \
    async16(gB + co, (nb) + 16384 + t16);                                     \
    async16(gB + cstep + co, (nb) + 20480 + t16);                             \
  }

  SV(lds, 0);
  SV(lds + 24576, 1);

  for (int kt = 0; kt < nkt; ++kt) {
    char* buf = lds + (kt & 1) * 24576;
    if (kt + 1 < nkt) waitvm<6>();  // tile kt landed; kt+1 (6 loads) in flight
    else waitvm<0>();
    barrier_mem();
    bf16x8 af[8], bfr[4];
#pragma unroll
    for (int m = 0; m < 8; ++m) {
      const int r = (wm << 7) + (m << 4) + lr;
      af[m] = *(const bf16x8*)(buf + r * 64 + SWZ(r));
    }
#pragma unroll
    for (int n = 0; n < 4; ++n) {
      const int rb = (wn << 6) + (n << 4) + lr;
      bfr[n] = *(const bf16x8*)(buf + 16384 + rb * 64 + SWZ(rb));
    }
    lgkm0_sb();
    barrier_mem();                  // all waves done reading buf -> safe to overwrite
    if (kt + 2 < nkt) SV(buf, kt + 2);
    __builtin_amdgcn_s_setprio(1);
#pragma unroll
    for (int m = 0; m < 8; ++m)
#pragma unroll
      for (int n = 0; n < 4; ++n)
        acc[m][n] = __builtin_amdgcn_mfma_f32_16x16x32_bf16(af[m], bfr[n], acc[m][n], 0, 0, 0);
    __builtin_amdgcn_s_setprio(0);
    __builtin_amdgcn_sched_barrier(0);
  }

  const int orow = row0 + (wm << 7) + (ks << 2);
  const int ocol = col0 + (wn << 6) + lr;
#pragma unroll
  for (int m = 0; m < 8; ++m) {
#pragma unroll
    for (int n = 0; n < 4; ++n) {
      const int c = ocol + (n << 4);
      const float bv = bias[c];
#pragma unroll
      for (int i = 0; i < 4; ++i) {
        const int r = orow + (m << 4) + i;
        outp[(size_t)r * N + c] = acc[m][n][i] + bv;
      }
    }
  }
#undef SV
}

// =============== dual GEMM: 256x128, BK=32, 4-ring, depth-3, M-partitioned ====
// bf16 out = (A@B1+b1)*silu(A@B2+b2). 512 thr, 8 waves (4M x 2N), wave 64x64 dual.
__global__ __launch_bounds__(512, 1) void dual8_k(const short* __restrict__ A,
                                                  const short* __restrict__ BT1,
                                                  const short* __restrict__ BT2,
                                                  const float* __restrict__ bias1,
                                                  const float* __restrict__ bias2,
                                                  short* __restrict__ outp,
                                                  int N, int K) {
  __shared__ __align__(16) char lds[4 * 32768];
  int bx, by;
  tile_map<16>(&bx, &by);
  const int row0 = by << 8, col0 = bx << 7;
  const int t = threadIdx.x, w = t >> 6, lane = t & 63;
  const int wm = w >> 1, wn = w & 1;
  const int lr = lane & 15, ks = lane >> 4;
  f32x4 acc1[4][4] = {}, acc2[4][4] = {};

  const int sslot = (t & 3) ^ ((t >> 3) & 3);
  const char* gA = (const char*)A + ((size_t)(row0 + (t >> 2)) * K) * 2 + sslot * 16;
  const char* gB1 = (const char*)BT1 + ((size_t)(col0 + (t >> 2)) * K) * 2 + sslot * 16;
  const char* gB2 = (const char*)BT2 + ((size_t)(col0 + (t >> 2)) * K) * 2 + sslot * 16;
  const size_t cstep = (size_t)K << 8;
  const int t16 = t << 4;
  const int nkt = K >> 5;

#define SAD(nb, kt)                                                           \
  {                                                                           \
    const size_t co = (size_t)(kt) << 6;                                      \
    async16(gA + co, (nb) + t16);                                             \
    async16(gA + cstep + co, (nb) + 8192 + t16);                              \
  }
#define SB1D(nb, kt) async16(gB1 + ((size_t)(kt) << 6), (nb) + 16384 + t16)
#define SB2D(nb, kt) async16(gB2 + ((size_t)(kt) << 6), (nb) + 24576 + t16)

  SAD(lds, 0); SB1D(lds, 0); SB2D(lds, 0);
  SAD(lds + 32768, 1); SB1D(lds + 32768, 1); SB2D(lds + 32768, 1);
  SAD(lds + 65536, 2); SB1D(lds + 65536, 2); SB2D(lds + 65536, 2);

  for (int kt = 0; kt < nkt; ++kt) {
    const char* base = lds + (kt & 3) * 32768;
    char* nb = lds + ((kt + 3) & 3) * 32768;
    const int rem = nkt - kt;
    bf16x8 af[4], bfr[4];
    if (rem > 2) waitvm<8>();
    else if (rem == 2) waitvm<4>();
    else waitvm<0>();
    barrier_mem();
    if (kt + 3 < nkt) SAD(nb, kt + 3);
#pragma unroll
    for (int n = 0; n < 4; ++n) {
      const int rb = (wn << 6) + (n << 4) + lr;
      bfr[n] = *(const bf16x8*)(base + 16384 + rb * 64 + SWZ(rb));
    }
#pragma unroll
    for (int m = 0; m < 4; ++m) {
      const int r = (wm << 6) + (m << 4) + lr;
      af[m] = *(const bf16x8*)(base + r * 64 + SWZ(r));
    }
    lgkm0_sb();
    __builtin_amdgcn_s_setprio(1);
#pragma unroll
    for (int m = 0; m < 4; ++m)
#pragma unroll
      for (int n = 0; n < 4; ++n)
        acc1[m][n] = __builtin_amdgcn_mfma_f32_16x16x32_bf16(af[m], bfr[n], acc1[m][n], 0, 0, 0);
    __builtin_amdgcn_s_setprio(0);
    __builtin_amdgcn_sched_barrier(0);
    barrier_mem();
    if (kt + 3 < nkt) { SB1D(nb, kt + 3); SB2D(nb, kt + 3); }
#pragma unroll
    for (int n = 0; n < 4; ++n) {
      const int rb = (wn << 6) + (n << 4) + lr;
      bfr[n] = *(const bf16x8*)(base + 24576 + rb * 64 + SWZ(rb));
    }
    lgkm0_sb();
    __builtin_amdgcn_s_setprio(1);
#pragma unroll
    for (int m = 0; m < 4; ++m)
#pragma unroll
      for (int n = 0; n < 4; ++n)
        acc2[m][n] = __builtin_amdgcn_mfma_f32_16x16x32_bf16(af[m], bfr[n], acc2[m][n], 0, 0, 0);
    __builtin_amdgcn_s_setprio(0);
    __builtin_amdgcn_sched_barrier(0);
  }

  const int orow = row0 + (wm << 6) + (ks << 2);
  const int ocol = col0 + (wn << 6) + lr;
#pragma unroll
  for (int m = 0; m < 4; ++m) {
#pragma unroll
    for (int n = 0; n < 4; ++n) {
      const int c = ocol + (n << 4);
      const float bv1 = bias1[c], bv2 = bias2[c];
#pragma unroll
      for (int i = 0; i < 4; ++i) {
        const int r = orow + (m << 4) + i;
        outp[(size_t)r * N + c] = f2bf((acc1[m][n][i] + bv1) * silu_f(acc2[m][n][i] + bv2));
      }
    }
  }
#undef SAD
#undef SB1D
#undef SB2D
}

// =============== TRIPLE shared-A GEMM (z, za, ya), counted waits ==============
__global__ __launch_bounds__(256, 2) void triple_k(const short* __restrict__ A,
                                                   const short* __restrict__ BT1,
                                                   const short* __restrict__ BT2,
                                                   const short* __restrict__ BT3,
                                                   const float* __restrict__ b1,
                                                   const float* __restrict__ b2,
                                                   const float* __restrict__ b3,
                                                   short* __restrict__ zout,
                                                   short* __restrict__ yaout,
                                                   int N, int K) {
  constexpr int PBB = 28672;  // A 4K + 3 x B 8K
  __shared__ __align__(16) char lds[2 * PBB];
  int bx, by;
  tile_map<64>(&bx, &by);
  const int row0 = by << 6, col0 = bx << 7;
  const int t = threadIdx.x, w = t >> 6, lane = t & 63;
  const int wr = w >> 1, wc = w & 1;
  const int lr = lane & 15, ks = lane >> 4;
  f32x4 acc1[2][4] = {}, acc2[2][4] = {}, acc3[2][4] = {};

  const int sslot = (t & 3) ^ ((t >> 3) & 3);
  const char* gA = (const char*)A + ((size_t)(row0 + (t >> 2)) * K) * 2 + sslot * 16;
  const size_t brow = ((size_t)(col0 + (t >> 2)) * K) * 2 + sslot * 16;
  const char* gB1 = (const char*)BT1 + brow;
  const char* gB2 = (const char*)BT2 + brow;
  const char* gB3 = (const char*)BT3 + brow;
  const size_t cstep = (size_t)K * 128;
  const int t16 = t << 4;
  const int nkt = K >> 5;

#define STA(nb, kt) async16(gA + (size_t)(kt) * 64, (nb) + t16)
#define STB(nb, kt, gp, off)                                                  \
  {                                                                           \
    const size_t co = (size_t)(kt) * 64;                                      \
    async16((gp) + co, (nb) + (off) + t16);                                   \
    async16((gp) + cstep + co, (nb) + (off) + 4096 + t16);                    \
  }

  { char* nb = lds; STA(nb, 0); STB(nb, 0, gB1, 4096); STB(nb, 0, gB2, 12288); STB(nb, 0, gB3, 20480); }

  for (int kt = 0; kt < nkt; ++kt) {
    const int ktn = kt + 1;
    const char* base = lds + (kt & 1) * PBB;
    char* nb = lds + (ktn & 1) * PBB;
    bf16x8 af[2], bfr[4];
    waitvm<4>();
    barrier_mem();
    if (ktn < nkt) { STA(nb, ktn); STB(nb, ktn, gB1, 4096); }
#pragma unroll
    for (int m = 0; m < 2; ++m) {
      const int r = (wr << 5) + (m << 4) + lr;
      af[m] = *(const bf16x8*)(base + r * 64 + SWZ(r));
    }
#pragma unroll
    for (int n = 0; n < 4; ++n) {
      const int rb = (wc << 6) + (n << 4) + lr;
      bfr[n] = *(const bf16x8*)(base + 4096 + rb * 64 + SWZ(rb));
    }
    lgkm0_sb();
    __builtin_amdgcn_s_setprio(1);
#pragma unroll
    for (int m = 0; m < 2; ++m)
#pragma unroll
      for (int n = 0; n < 4; ++n)
        acc1[m][n] = __builtin_amdgcn_mfma_f32_16x16x32_bf16(af[m], bfr[n], acc1[m][n], 0, 0, 0);
    __builtin_amdgcn_s_setprio(0);
    __builtin_amdgcn_sched_barrier(0);
    if (ktn < nkt) waitvm<5>();
    else waitvm<2>();
    barrier_mem();
    if (ktn < nkt) STB(nb, ktn, gB2, 12288);
#pragma unroll
    for (int n = 0; n < 4; ++n) {
      const int rb = (wc << 6) + (n << 4) + lr;
      bfr[n] = *(const bf16x8*)(base + 12288 + rb * 64 + SWZ(rb));
    }
    lgkm0_sb();
    __builtin_amdgcn_s_setprio(1);
#pragma unroll
    for (int m = 0; m < 2; ++m)
#pragma unroll
      for (int n = 0; n < 4; ++n)
        acc2[m][n] = __builtin_amdgcn_mfma_f32_16x16x32_bf16(af[m], bfr[n], acc2[m][n], 0, 0, 0);
    __builtin_amdgcn_s_setprio(0);
    __builtin_amdgcn_sched_barrier(0);
    if (ktn < nkt) waitvm<5>();
    else waitvm<0>();
    barrier_mem();
    if (ktn < nkt) STB(nb, ktn, gB3, 20480);
#pragma unroll
    for (int n = 0; n < 4; ++n) {
      const int rb = (wc << 6) + (n << 4) + lr;
      bfr[n] = *(const bf16x8*)(base + 20480 + rb * 64 + SWZ(rb));
    }
    lgkm0_sb();
    __builtin_amdgcn_s_setprio(1);
#pragma unroll
    for (int m = 0; m < 2; ++m)
#pragma unroll
      for (int n = 0; n < 4; ++n)
        acc3[m][n] = __builtin_amdgcn_mfma_f32_16x16x32_bf16(af[m], bfr[n], acc3[m][n], 0, 0, 0);
    __builtin_amdgcn_s_setprio(0);
    __builtin_amdgcn_sched_barrier(0);
  }

  const int orow = row0 + (wr << 5) + (ks << 2);
  const int ocol = col0 + (wc << 6) + lr;
#pragma unroll
  for (int m = 0; m < 2; ++m) {
#pragma unroll
    for (int n = 0; n < 4; ++n) {
      const int c = ocol + (n << 4);
      const float bv1 = b1[c], bv2 = b2[c], bv3 = b3[c];
#pragma unroll
      for (int i = 0; i < 4; ++i) {
        const int r = orow + (m << 4) + i;
        const size_t idx = (size_t)r * N + c;
        zout[idx] = f2bf((acc1[m][n][i] + bv1) * silu_f(acc2[m][n][i] + bv2));
        yaout[idx] = f2bf(acc3[m][n][i] + bv3);
      }
    }
  }
#undef STA
#undef STB
}

// ---------------- 4-wave single GEMM -------------------------------------------
// MODE 0: out_f32 = v ;  MODE 3: out_f32 += v*silu(aux bf16) ;  MODE 4: out_f32 += v
template <int MODE, int BM, int BN, int WM, int WN, int NBUF>
__global__ __launch_bounds__(256, 2) void gemm_k(const short* __restrict__ A,
                                                 const short* __restrict__ BT,
                                                 const float* __restrict__ bias,
                                                 const short* __restrict__ aux,
                                                 void* __restrict__ outp,
                                                 int N, int K) {
  constexpr int MF = WM / 16, NF = WN / 16;
  constexpr int NWN = BN / WN;
  constexpr int PBB = (BM + BN) * 64;
  constexpr int DEPTH = NBUF - 1;
  constexpr int L = (BM + BN) / 64;
  static_assert((BM / WM) * (BN / WN) == 4, "4 waves");
  __shared__ __align__(16) char lds[NBUF * PBB];
  int bx, by;
  tile_map<4096 / BM>(&bx, &by);
  const int row0 = by * BM, col0 = bx * BN;
  const int t = threadIdx.x, w = t >> 6, lane = t & 63;
  const int wr = w / NWN, wc = w % NWN;
  f32x4 acc[MF][NF] = {};

  const int sslot = (t & 3) ^ ((t >> 3) & 3);
  const char* gA0 = (const char*)A + ((size_t)(row0 + (t >> 2)) * K) * 2 + sslot * 16;
  const char* gB0 = (const char*)BT + ((size_t)(col0 + (t >> 2)) * K) * 2 + sslot * 16;
  const size_t ccstep = (size_t)K * 128;
  const int wb = w << 10;
  const int lr = lane & 15, ks = lane >> 4;

  const int NIT = K >> 5;
  auto stage = [&](int buf, int it) {
    char* dst = lds + buf * PBB;
    const size_t io = (size_t)it * 64;
#pragma unroll
    for (int cc = 0; cc < BM / 64; ++cc)
      async16(gA0 + io + cc * ccstep, dst + cc * 4096 + wb);
#pragma unroll
    for (int cc = 0; cc < BN / 64; ++cc)
      async16(gB0 + io + cc * ccstep, dst + BM * 64 + cc * 4096 + wb);
  };

#pragma unroll
  for (int pit = 0; pit < DEPTH; ++pit) stage(pit, pit);

  for (int it = 0; it < NIT; ++it) {
    const int rem = NIT - it;
    if (rem >= DEPTH + 1) waitvm<L * (DEPTH - 1)>();
    else if (rem >= 2) waitvm<L>();
    else waitvm<0>();
    barrier_mem();
    if (it + DEPTH < NIT) stage((it + DEPTH) % NBUF, it + DEPTH);
    const char* base = lds + (it % NBUF) * PBB;
    bf16x8 af[MF], bfr[NF];
#pragma unroll
    for (int m = 0; m < MF; ++m) {
      const int r = wr * WM + m * 16 + lr;
      af[m] = *(const bf16x8*)(base + r * 64 + SWZ(r));
    }
#pragma unroll
    for (int n = 0; n < NF; ++n) {
      const int r = wc * WN + n * 16 + lr;
      bfr[n] = *(const bf16x8*)(base + BM * 64 + r * 64 + SWZ(r));
    }
    lgkm0_sb();
    __builtin_amdgcn_s_setprio(1);
#pragma unroll
    for (int m = 0; m < MF; ++m)
#pragma unroll
      for (int n = 0; n < NF; ++n)
        acc[m][n] = __builtin_amdgcn_mfma_f32_16x16x32_bf16(af[m], bfr[n], acc[m][n], 0, 0, 0);
    __builtin_amdgcn_s_setprio(0);
    __builtin_amdgcn_sched_barrier(0);
  }

  const int orow = row0 + wr * WM + (ks << 2);
  const int ocol = col0 + wc * WN + lr;
#pragma unroll
  for (int m = 0; m < MF; ++m) {
#pragma unroll
    for (int n = 0; n < NF; ++n) {
      const int c = ocol + (n << 4);
      const float bv = bias[c];
#pragma unroll
      for (int i = 0; i < 4; ++i) {
        const int r = orow + (m << 4) + i;
        const size_t idx = (size_t)r * N + c;
        float v = acc[m][n][i] + bv;
        if (MODE == 0) ((float*)outp)[idx] = v;
        else if (MODE == 3) ((float*)outp)[idx] += v * silu_f(bf2f(aux[idx]));
        else ((float*)outp)[idx] += v;
      }
    }
  }
}

// ------------- transpose-convert: W(R,C) fp32 -> WT(C,R) bf16 ------------------
__global__ __launch_bounds__(256) void transp_k(const float* __restrict__ W,
                                                short* __restrict__ WT,
                                                int R, int C) {
  __shared__ float tile[32][33];
  const size_t moff = (size_t)blockIdx.z * R * C;
  const float* Wp = W + moff;
  short* Tp = WT + moff;
  const int c0 = blockIdx.x << 5, r0 = blockIdx.y << 5;
  const int tx = threadIdx.x, ty = threadIdx.y;
#pragma unroll
  for (int i = 0; i < 4; ++i)
    tile[ty + 8 * i][tx] = Wp[(size_t)(r0 + ty + 8 * i) * C + (c0 + tx)];
  __syncthreads();
#pragma unroll
  for (int i = 0; i < 4; ++i)
    Tp[(size_t)(c0 + ty + 8 * i) * R + (r0 + tx)] = f2bf(tile[tx][ty + 8 * i]);
}

// ------------- embedding with max_norm=1 renorm -------------------------------
__global__ __launch_bounds__(256) void embed_k(const int* __restrict__ tok,
                                               const float* __restrict__ emb,
                                               float* __restrict__ x) {
  const int row = blockIdx.x, t = threadIdx.x, w = t >> 6, lane = t & 63;
  const int token = tok[row];
  float4 v = ((const float4*)(emb + (size_t)token * 1024))[t];
  float ss = v.x * v.x + v.y * v.y + v.z * v.z + v.w * v.w;
#pragma unroll
  for (int off = 32; off; off >>= 1) ss += __shfl_xor(ss, off, 64);
  __shared__ float red[4];
  if (lane == 0) red[w] = ss;
  __syncthreads();
  const float nrm = sqrtf(red[0] + red[1] + red[2] + red[3]);
  const float sc = fminf(1.0f, 1.0f / fmaxf(nrm, 1e-7f));
  v.x *= sc; v.y *= sc; v.z *= sc; v.w *= sc;
  ((float4*)(x + (size_t)row * 1024))[t] = v;
}

// ------------- RMSNorm row kernel (fp32 or bf16 input) -> bf16 out -------------
template <int BF>
__global__ __launch_bounds__(256) void rms_k(const void* __restrict__ xin,
                                             const float* __restrict__ g,
                                             short* __restrict__ o) {
  const int row = blockIdx.x, t = threadIdx.x, w = t >> 6, lane = t & 63;
  float v0, v1, v2, v3;
  if (BF) {
    short4 s = ((const short4*)((const short*)xin + (size_t)row * 1024))[t];
    v0 = bf2f(s.x); v1 = bf2f(s.y); v2 = bf2f(s.z); v3 = bf2f(s.w);
  } else {
    float4 v = ((const float4*)((const float*)xin + (size_t)row * 1024))[t];
    v0 = v.x; v1 = v.y; v2 = v.z; v3 = v.w;
  }
  float ss = v0 * v0 + v1 * v1 + v2 * v2 + v3 * v3;
#pragma unroll
  for (int off = 32; off; off >>= 1) ss += __shfl_xor(ss, off, 64);
  __shared__ float red[4];
  if (lane == 0) red[w] = ss;
  __syncthreads();
  const float sc = rsqrtf((red[0] + red[1] + red[2] + red[3]) * (1.0f / 1024.0f) + 1e-6f);
  float4 gv = ((const float4*)g)[t];
  short4 ov = make_short4(f2bf(v0 * sc * gv.x), f2bf(v1 * sc * gv.y),
                          f2bf(v2 * sc * gv.z), f2bf(v3 * sc * gv.w));
  *(short4*)(o + (size_t)row * 1024 + 4 * t) = ov;
}

// ------------- final LayerNorm: fp32 in -> bf16 out ---------------------------
__global__ __launch_bounds__(256) void ln_k(const float* __restrict__ x,
                                            const float* __restrict__ lw,
                                            const float* __restrict__ lb,
                                            short* __restrict__ o) {
  const int row = blockIdx.x, t = threadIdx.x, w = t >> 6, lane = t & 63;
  float4 v = ((const float4*)(x + (size_t)row * 1024))[t];
  float s1 = v.x + v.y + v.z + v.w;
  float s2 = v.x * v.x + v.y * v.y + v.z * v.z + v.w * v.w;
#pragma unroll
  for (int off = 32; off; off >>= 1) {
    s1 += __shfl_xor(s1, off, 64);
    s2 += __shfl_xor(s2, off, 64);
  }
  __shared__ float red[8];
  if (lane == 0) { red[w] = s1; red[4 + w] = s2; }
  __syncthreads();
  const float mu = (red[0] + red[1] + red[2] + red[3]) * (1.0f / 1024.0f);
  const float ex2 = (red[4] + red[5] + red[6] + red[7]) * (1.0f / 1024.0f);
  const float rs = rsqrtf(ex2 - mu * mu + 1e-5f);
  float4 wv = ((const float4*)lw)[t];
  float4 bv = ((const float4*)lb)[t];
  short4 ov = make_short4(f2bf((v.x - mu) * rs * wv.x + bv.x),
                          f2bf((v.y - mu) * rs * wv.y + bv.y),
                          f2bf((v.z - mu) * rs * wv.z + bv.z),
                          f2bf((v.w - mu) * rs * wv.w + bv.w));
  *(short4*)(o + (size_t)row * 1024 + 4 * t) = ov;
}

// ------------- SConv IIR scan, 2-kernel chunked, bf16 storage ------------------
DEVI void decay_of(int d, float* dr, float* di) {
  const float ang = powf(1e-3f, (float)d * (1.0f / 1023.0f));
  float sn, cs;
  sincosf(ang, &sn, &cs);
  const float mag = expf(1e-5f);
  *dr = mag * cs; *di = mag * sn;
}

__global__ __launch_bounds__(256) void s1_k(const short* __restrict__ z,
                                            float* __restrict__ Er, float* __restrict__ Ei) {
  const int d = (blockIdx.x << 8) + threadIdx.x;
  const int c = blockIdx.y, b = blockIdx.z;
  float dr, di;
  decay_of(d, &dr, &di);
  const short* zp = z + ((size_t)(b * 2048 + c * 64) << 10) + d;
  float sr = 0.0f, si = 0.0f;
  for (int k = 0; k < 64; ++k) {
    float zv = bf2f(zp[(size_t)k << 10]);
    float nr = dr * sr - di * si + zv;
    si = dr * si + di * sr;
    sr = nr;
  }
  const int idx = ((b << 5) + c) * 1024 + d;
  Er[idx] = sr; Ei[idx] = si;
}

// s3 with fused seed-scan: seed = sum_{c'<c} A64^(c-1-c') E[c']
__global__ __launch_bounds__(256) void s3_k(const short* __restrict__ z,
                                            const float* __restrict__ Er,
                                            const float* __restrict__ Ei,
                                            const float* __restrict__ lcre,
                                            const float* __restrict__ lcim,
                                            short* __restrict__ h) {
  const int d = (blockIdx.x << 8) + threadIdx.x;
  const int c = blockIdx.y, b = blockIdx.z;
  float dr, di;
  decay_of(d, &dr, &di);
  float ar = dr, ai = di;
#pragma unroll
  for (int q = 0; q < 6; ++q) { float nr = ar * ar - ai * ai; ai = 2.0f * ar * ai; ar = nr; }
  float sr = 0.0f, si = 0.0f;
  for (int cc = 0; cc < c; ++cc) {
    const int eidx = ((b << 5) + cc) * 1024 + d;
    const float er = Er[eidx], ei = Ei[eidx];
    const float nr = ar * sr - ai * si + er;
    si = ar * si + ai * sr + ei;
    sr = nr;
  }
  float wr = 1.0f, wi = 0.0f, br = ar, bi = ai;
  int e = c;
  while (e) {
    if (e & 1) { float nr = wr * br - wi * bi; wi = wr * bi + wi * br; wr = nr; }
    float nb = br * br - bi * bi; bi = 2.0f * br * bi; br = nb;
    e >>= 1;
  }
  { float nr = wr * dr - wi * di; wi = wr * di + wi * dr; wr = nr; }
  const float lr_ = lcre[d], li_ = lcim[d];
  const size_t base = ((size_t)(b * 2048 + c * 64) << 10) + d;
  for (int k = 0; k < 64; ++k) {
    const float zv = bf2f(z[base + ((size_t)k << 10)]);
    const float nr = dr * sr - di * si + zv;
    si = dr * si + di * sr;
    sr = nr;
    h[base + ((size_t)k << 10)] = f2bf(sr + lr_ * wr - li_ * wi);
    const float nw = wr * dr - wi * di;
    wi = wr * di + wi * dr;
    wr = nw;
  }
}

extern "C" void kernel_launch(void* const* d_in, const int* in_sizes, int n_in,
                              void* d_out, int out_size, void* d_ws, size_t ws_size,
                              hipStream_t stream) {
  const int* tokens = (const int*)d_in[0];
  const float* emb = (const float*)d_in[1];
  const float* Wz = (const float*)d_in[2];
  const float* bz = (const float*)d_in[3];
  const float* Wza = (const float*)d_in[4];
  const float* bza = (const float*)d_in[5];
  const float* Wy = (const float*)d_in[6];
  const float* by = (const float*)d_in[7];
  const float* Wya = (const float*)d_in[8];
  const float* bya = (const float*)d_in[9];
  const float* lc_re = (const float*)d_in[10];
  const float* lc_im = (const float*)d_in[11];
  const float* g_in = (const float*)d_in[12];
  const float* g_sc = (const float*)d_in[13];
  const float* g_ffn = (const float*)d_in[14];
  const float* Wf = (const float*)d_in[15];
  const float* bf = (const float*)d_in[16];
  const float* Wfa = (const float*)d_in[17];
  const float* bfa = (const float*)d_in[18];
  const float* Wfo = (const float*)d_in[19];
  const float* bfo = (const float*)d_in[20];
  const float* ln_w = (const float*)d_in[21];
  const float* ln_b = (const float*)d_in[22];
  const float* Wout = (const float*)d_in[23];
  const float* bout = (const float*)d_in[24];

  char* p = (char*)d_ws;
  float* xb = (float*)p;   p += (size_t)4096 * 1024 * 4;
  short* zb = (short*)p;   p += (size_t)4096 * 1024 * 2;
  short* hb = (short*)p;   p += (size_t)4096 * 1024 * 2;
  short* yab = (short*)p;  p += (size_t)4096 * 1024 * 2;
  float* Er = (float*)p;   p += (size_t)2 * 32 * 1024 * 4;
  float* Ei = (float*)p;   p += (size_t)2 * 32 * 1024 * 4;
  short* xnb = (short*)p;  p += (size_t)4096 * 1024 * 2;
  short* hnb = (short*)p;  p += (size_t)4096 * 1024 * 2;
  short* gb = (short*)p;   p += (size_t)4096 * 4096 * 2;
  short* WzT = (short*)p;  p += (size_t)4 * 1024 * 1024 * 2;
  short* WzaT = (short*)p; p += (size_t)4 * 1024 * 1024 * 2;
  short* WyT = (short*)p;  p += (size_t)4 * 1024 * 1024 * 2;
  short* WyaT = (short*)p; p += (size_t)4 * 1024 * 1024 * 2;
  short* WfT = (short*)p;  p += (size_t)4 * 1024 * 4096 * 2;
  short* WfaT = (short*)p; p += (size_t)4 * 1024 * 4096 * 2;
  short* WfoT = (short*)p; p += (size_t)4 * 1024 * 4096 * 2;
  short* WoutT = (short*)p; p += (size_t)32000 * 1024 * 2;

  const dim3 tb(32, 8);
  transp_k<<<dim3(32, 32, 4), tb, 0, stream>>>(Wz, WzT, 1024, 1024);
  transp_k<<<dim3(32, 32, 4), tb, 0, stream>>>(Wza, WzaT, 1024, 1024);
  transp_k<<<dim3(32, 32, 4), tb, 0, stream>>>(Wy, WyT, 1024, 1024);
  transp_k<<<dim3(32, 32, 4), tb, 0, stream>>>(Wya, WyaT, 1024, 1024);
  transp_k<<<dim3(128, 32, 4), tb, 0, stream>>>(Wf, WfT, 1024, 4096);
  transp_k<<<dim3(128, 32, 4), tb, 0, stream>>>(Wfa, WfaT, 1024, 4096);
  transp_k<<<dim3(32, 128, 4), tb, 0, stream>>>(Wfo, WfoT, 4096, 1024);
  transp_k<<<dim3(1000, 32, 1), tb, 0, stream>>>(Wout, WoutT, 1024, 32000);

  embed_k<<<4096, 256, 0, stream>>>(tokens, emb, xb);

  for (int i = 0; i < 4; ++i) {
    const size_t dd = (size_t)i * 1024 * 1024;
    const size_t dv = (size_t)i * 1024;
    const size_t dw = (size_t)i * 1024 * 4096;
    const size_t df = (size_t)i * 4096;
    rms_k<0><<<4096, 256, 0, stream>>>(xb, g_sc + dv, xnb);
    // z = (xn@Wz+bz)*silu(xn@Wza+bza); yapre = xn@Wya+bya
    triple_k<<<512, 256, 0, stream>>>(xnb, WzT + dd, WzaT + dd, WyaT + dd,
                                      bz + dv, bza + dv, bya + dv, zb, yab, 1024, 1024);
    s1_k<<<dim3(4, 32, 2), 256, 0, stream>>>(zb, Er, Ei);
    s3_k<<<dim3(4, 32, 2), 256, 0, stream>>>(zb, Er, Ei, lc_re + dv, lc_im + dv, hb);
    rms_k<1><<<4096, 256, 0, stream>>>(hb, g_in + dv, hnb);
    // x += (hn@Wy+by) * silu(yapre)
    gemm_k<3, 64, 128, 32, 64, 3><<<512, 256, 0, stream>>>(
        hnb, WyT + dd, by + dv, yab, xb, 1024, 1024);
    rms_k<0><<<4096, 256, 0, stream>>>(xb, g_ffn + dv, xnb);
    // g = (xn@Wf+bf) * silu(xn@Wfa+bfa) -> bf16
    dual8_k<<<512, 512, 0, stream>>>(xnb, WfT + dw, WfaT + dw, bf + df, bfa + df,
                                     gb, 4096, 1024);
    // x += g@Wfo + bfo
    gemm_k<4, 64, 128, 32, 64, 4><<<512, 256, 0, stream>>>(
        gb, WfoT + dw, bfo + dv, nullptr, xb, 1024, 4096);
  }

  ln_k<<<4096, 256, 0, stream>>>(xb, ln_w, ln_b, xnb);
  // vocab: voc v5 — M-partitioned XCD map (A L2-resident per XCD)
  voc_k<<<4000, 256, 0, stream>>>(xnb, WoutT, bout, (float*)d_out, 32000, 1024);

  (void)in_sizes; (void)n_in; (void)out_size; (void)ws_size;
}